// Round 1
// baseline (3247.640 us; speedup 1.0000x reference)
//
#include <hip/hip_runtime.h>

#define N_NODES 20000
#define E_EDGES 160000
#define IN_CH 128
#define H_HEADS 8
#define C_CH 64
#define HC 512
#define M_TOT (E_EDGES + N_NODES)
#define NEG_SLOPE 0.2f

// ---------------- K0: init workspace + out=bias ----------------
__global__ void k0_init(float* __restrict__ out, const float* __restrict__ bias,
                        float* __restrict__ loop_attr, float* __restrict__ cnt,
                        unsigned* __restrict__ lmax_key, float* __restrict__ denom) {
    int idx = blockIdx.x * blockDim.x + threadIdx.x;
    if (idx < N_NODES * HC) out[idx] = bias[idx & (HC - 1)];
    if (idx < N_NODES * IN_CH) loop_attr[idx] = 0.f;
    if (idx < N_NODES * H_HEADS) { lmax_key[idx] = 0x007FFFFFu; denom[idx] = 0.f; }
    if (idx < N_NODES) cnt[idx] = 0.f;
}

// ---------------- K1: per-dst sums of edge_attr + in-degree ----------------
__global__ void k1_deg(const int* __restrict__ ei, const float* __restrict__ ea,
                       float* __restrict__ loop_attr, float* __restrict__ cnt) {
    int idx = blockIdx.x * blockDim.x + threadIdx.x;
    if (idx >= E_EDGES * IN_CH) return;
    int e = idx >> 7, c = idx & (IN_CH - 1);
    int dst = ei[E_EDGES + e];
    atomicAdd(&loop_attr[dst * IN_CH + c], ea[idx]);
    if (c == 0) atomicAdd(&cnt[dst], 1.0f);
}

// ---------------- K2: loop_attr = sum / max(cnt,1) ----------------
__global__ void k2_div(float* __restrict__ loop_attr, const float* __restrict__ cnt) {
    int idx = blockIdx.x * blockDim.x + threadIdx.x;
    if (idx >= N_NODES * IN_CH) return;
    loop_attr[idx] /= fmaxf(cnt[idx >> 7], 1.0f);
}

// ---------------- K3: fp32 tiled GEMM  C[M,512] = A[M,128] @ B[128,512] ----------------
__global__ void k3_gemm(const float* __restrict__ A, const float* __restrict__ B,
                        float* __restrict__ C, int M) {
    __shared__ float As[16][64 + 1];
    __shared__ float Bs[16][64 + 1];
    int row0 = blockIdx.x * 64, col0 = blockIdx.y * 64;
    int t = threadIdx.x;
    int tx = t & 15, ty = t >> 4;
    float acc[4][4] = {};
    for (int k0 = 0; k0 < 128; k0 += 16) {
        for (int i = 0; i < 4; ++i) {
            int idx = t * 4 + i;
            int m = idx >> 4, k = idx & 15;
            int gr = row0 + m;
            As[k][m] = (gr < M) ? A[gr * 128 + k0 + k] : 0.f;
        }
        for (int i = 0; i < 4; ++i) {
            int idx = t * 4 + i;
            int k = idx >> 6, n = idx & 63;
            Bs[k][n] = B[(k0 + k) * 512 + col0 + n];
        }
        __syncthreads();
        for (int k = 0; k < 16; ++k) {
            float a[4], b[4];
            for (int i = 0; i < 4; ++i) a[i] = As[k][ty * 4 + i];
            for (int j = 0; j < 4; ++j) b[j] = Bs[k][tx * 4 + j];
            for (int i = 0; i < 4; ++i)
                for (int j = 0; j < 4; ++j) acc[i][j] += a[i] * b[j];
        }
        __syncthreads();
    }
    for (int i = 0; i < 4; ++i) {
        int gr = row0 + ty * 4 + i;
        if (gr < M)
            for (int j = 0; j < 4; ++j) C[gr * 512 + col0 + tx * 4 + j] = acc[i][j];
    }
}

// ---------------- K4: edge GEMM fused with GATv2 scoring -> logits[M_TOT, 8] ----------------
__global__ void k4_logits(const int* __restrict__ ei, const float* __restrict__ ea,
                          const float* __restrict__ loop_attr,
                          const float* __restrict__ xl, const float* __restrict__ xr,
                          const float* __restrict__ We, const float* __restrict__ att,
                          float* __restrict__ logits) {
    __shared__ float Ea[64][IN_CH + 1];
    __shared__ float Bs[16][64 + 1];
    __shared__ int s_src[64], s_dst[64];
    int row0 = blockIdx.x * 64;
    int t = threadIdx.x;

    if (t < 64) {
        int ge = row0 + t;
        int s = 0, d = 0;
        if (ge < E_EDGES) { s = ei[ge]; d = ei[E_EDGES + ge]; }
        else if (ge < M_TOT) { s = d = ge - E_EDGES; }
        s_src[t] = s; s_dst[t] = d;
    }
    for (int i = 0; i < 32; ++i) {
        int idx = t + i * 256;                  // 0 .. 8191
        int r = idx >> 7, c = idx & 127;
        int ge = row0 + r;
        float v = 0.f;
        if (ge < E_EDGES) v = ea[ge * 128 + c];
        else if (ge < M_TOT) v = loop_attr[(ge - E_EDGES) * 128 + c];
        Ea[r][c] = v;
    }
    __syncthreads();

    int tx = t & 15, ty = t >> 4;
    for (int h = 0; h < H_HEADS; ++h) {
        float acc[4][4] = {};
        for (int k0 = 0; k0 < 128; k0 += 16) {
            for (int i = 0; i < 4; ++i) {
                int idx = t * 4 + i;
                int k = idx >> 6, n = idx & 63;
                Bs[k][n] = We[(k0 + k) * 512 + h * 64 + n];
            }
            __syncthreads();
            for (int k = 0; k < 16; ++k) {
                float a[4], b[4];
                for (int i = 0; i < 4; ++i) a[i] = Ea[ty * 4 + i][k0 + k];
                for (int j = 0; j < 4; ++j) b[j] = Bs[k][tx * 4 + j];
                for (int i = 0; i < 4; ++i)
                    for (int j = 0; j < 4; ++j) acc[i][j] += a[i] * b[j];
            }
            __syncthreads();
        }
        // epilogue: m = leaky(acc + xl[src] + xr[dst]); partial = att . m
        float part[4];
        for (int i = 0; i < 4; ++i) {
            int r = ty * 4 + i;
            int s = s_src[r], d = s_dst[r];
            float sum = 0.f;
            for (int j = 0; j < 4; ++j) {
                int c = tx * 4 + j;
                float v = acc[i][j] + xl[s * 512 + h * 64 + c] + xr[d * 512 + h * 64 + c];
                v = (v > 0.f) ? v : v * NEG_SLOPE;
                sum += att[h * 64 + c] * v;
            }
            part[i] = sum;
        }
        for (int m = 1; m < 16; m <<= 1)
            for (int i = 0; i < 4; ++i) part[i] += __shfl_xor(part[i], m, 64);
        if (tx == 0) {
            for (int i = 0; i < 4; ++i) {
                int ge = row0 + ty * 4 + i;
                if (ge < M_TOT) logits[ge * 8 + h] = part[i];
            }
        }
    }
}

// ---------------- K5: segment max via order-preserving uint atomicMax ----------------
__device__ __forceinline__ unsigned f2key(float f) {
    unsigned u = __float_as_uint(f);
    return (u & 0x80000000u) ? ~u : (u | 0x80000000u);
}
__device__ __forceinline__ float key2f(unsigned key) {
    unsigned u = (key & 0x80000000u) ? (key ^ 0x80000000u) : ~key;
    return __uint_as_float(u);
}

__global__ void k5_max(const int* __restrict__ ei, const float* __restrict__ logits,
                       unsigned* __restrict__ lmax_key) {
    int idx = blockIdx.x * blockDim.x + threadIdx.x;
    if (idx >= M_TOT * 8) return;
    int e = idx >> 3, h = idx & 7;
    int d = (e < E_EDGES) ? ei[E_EDGES + e] : e - E_EDGES;
    atomicMax(&lmax_key[d * 8 + h], f2key(logits[idx]));
}

// ---------------- K6: segment sum of exp ----------------
__global__ void k6_denom(const int* __restrict__ ei, const float* __restrict__ logits,
                         const unsigned* __restrict__ lmax_key, float* __restrict__ denom) {
    int idx = blockIdx.x * blockDim.x + threadIdx.x;
    if (idx >= M_TOT * 8) return;
    int e = idx >> 3, h = idx & 7;
    int d = (e < E_EDGES) ? ei[E_EDGES + e] : e - E_EDGES;
    float m = key2f(lmax_key[d * 8 + h]);
    atomicAdd(&denom[d * 8 + h], expf(logits[idx] - m));
}

// ---------------- K7: weighted scatter aggregation ----------------
__global__ void k7_agg(const int* __restrict__ ei, const float* __restrict__ logits,
                       const unsigned* __restrict__ lmax_key, const float* __restrict__ denom,
                       const float* __restrict__ xl, float* __restrict__ out) {
    int idx = blockIdx.x * blockDim.x + threadIdx.x;
    if (idx >= M_TOT * 64) return;
    int e = idx >> 6;
    int sub = idx & 63;
    int h = sub >> 3, c0 = (sub & 7) * 8;
    int s, d;
    if (e < E_EDGES) { s = ei[e]; d = ei[E_EDGES + e]; }
    else { s = d = e - E_EDGES; }
    float m = key2f(lmax_key[d * 8 + h]);
    float alpha = expf(logits[e * 8 + h] - m) / denom[d * 8 + h];
    const float* xs = xl + s * 512 + h * 64 + c0;
    float* op = out + d * 512 + h * 64 + c0;
    for (int j = 0; j < 8; ++j) atomicAdd(&op[j], alpha * xs[j]);
}

extern "C" void kernel_launch(void* const* d_in, const int* in_sizes, int n_in,
                              void* d_out, int out_size, void* d_ws, size_t ws_size,
                              hipStream_t stream) {
    const float* x    = (const float*)d_in[0];
    const int*   ei   = (const int*)d_in[1];
    const float* ea   = (const float*)d_in[2];
    const float* Wl   = (const float*)d_in[3];
    const float* Wr   = (const float*)d_in[4];
    const float* We   = (const float*)d_in[5];
    const float* att  = (const float*)d_in[6];
    const float* bias = (const float*)d_in[7];
    float* out = (float*)d_out;

    float* xl        = (float*)d_ws;                    // N*512
    float* xr        = xl + (size_t)N_NODES * HC;       // N*512
    float* loop_attr = xr + (size_t)N_NODES * HC;       // N*128
    float* cnt       = loop_attr + (size_t)N_NODES * IN_CH;  // N
    float* logits    = cnt + N_NODES;                   // M_TOT*8
    unsigned* lmax   = (unsigned*)(logits + (size_t)M_TOT * 8); // N*8
    float* denom     = (float*)lmax + (size_t)N_NODES * 8;      // N*8

    const int B = 256;
    k0_init<<<(N_NODES * HC + B - 1) / B, B, 0, stream>>>(out, bias, loop_attr, cnt, lmax, denom);
    k1_deg<<<(E_EDGES * IN_CH + B - 1) / B, B, 0, stream>>>(ei, ea, loop_attr, cnt);
    k2_div<<<(N_NODES * IN_CH + B - 1) / B, B, 0, stream>>>(loop_attr, cnt);
    k3_gemm<<<dim3((N_NODES + 63) / 64, 8), B, 0, stream>>>(x, Wl, xl, N_NODES);
    k3_gemm<<<dim3((N_NODES + 63) / 64, 8), B, 0, stream>>>(x, Wr, xr, N_NODES);
    k4_logits<<<(M_TOT + 63) / 64, B, 0, stream>>>(ei, ea, loop_attr, xl, xr, We, att, logits);
    k5_max<<<(M_TOT * 8 + B - 1) / B, B, 0, stream>>>(ei, logits, lmax);
    k6_denom<<<(M_TOT * 8 + B - 1) / B, B, 0, stream>>>(ei, logits, lmax, denom);
    k7_agg<<<(M_TOT * 64 + B - 1) / B, B, 0, stream>>>(ei, logits, lmax, denom, xl, out);
}

// Round 2
// 832.382 us; speedup vs baseline: 3.9016x; 3.9016x over previous
//
#include <hip/hip_runtime.h>

#define N_NODES 20000
#define E_EDGES 160000
#define IN_CH 128
#define H_HEADS 8
#define C_CH 64
#define HC 512
#define M_TOT (E_EDGES + N_NODES)
#define NEG_SLOPE 0.2f

// ---------------- K0: zero degree ----------------
__global__ void k_zero(int* __restrict__ deg) {
    int i = blockIdx.x * blockDim.x + threadIdx.x;
    if (i < N_NODES) deg[i] = 0;
}

// ---------------- K1: in-degree count ----------------
__global__ void k_deg(const int* __restrict__ ei, int* __restrict__ deg) {
    int e = blockIdx.x * blockDim.x + threadIdx.x;
    if (e >= E_EDGES) return;
    atomicAdd(&deg[ei[E_EDGES + e]], 1);
}

// ---------------- K2: single-block prefix scan -> rowptr, place self-loops ----------------
__global__ void k_scan(const int* __restrict__ deg, int* __restrict__ rowptr,
                       int* __restrict__ cursor, int* __restrict__ eidx) {
    __shared__ int buf[256];
    __shared__ int carry;
    int tid = threadIdx.x;
    if (tid == 0) carry = 0;
    __syncthreads();
    for (int base = 0; base < N_NODES; base += 256) {
        int i = base + tid;
        int v = (i < N_NODES) ? (deg[i] + 1) : 0;   // +1 = self loop
        buf[tid] = v;
        __syncthreads();
        for (int off = 1; off < 256; off <<= 1) {
            int t = (tid >= off) ? buf[tid - off] : 0;
            __syncthreads();
            buf[tid] += t;
            __syncthreads();
        }
        int c = carry;
        int incl = buf[tid] + c;
        int excl = incl - v;
        if (i < N_NODES) {
            rowptr[i] = excl;
            eidx[excl] = E_EDGES + i;   // self-loop edge id in slot 0 of segment
            cursor[i] = excl + 1;
        }
        __syncthreads();
        if (tid == 0) carry = c + buf[255];
        __syncthreads();
    }
    if (tid == 0) rowptr[N_NODES] = carry;
}

// ---------------- K3: CSR fill ----------------
__global__ void k_fill(const int* __restrict__ ei, int* __restrict__ cursor,
                       int* __restrict__ eidx) {
    int e = blockIdx.x * blockDim.x + threadIdx.x;
    if (e >= E_EDGES) return;
    int slot = atomicAdd(&cursor[ei[E_EDGES + e]], 1);
    eidx[slot] = e;
}

// ---------------- K4: loop_attr = mean of incoming edge_attr (CSR gather) ----------------
__global__ void k_loop_attr(const int* __restrict__ rowptr, const int* __restrict__ eidx,
                            const float* __restrict__ ea, float* __restrict__ loop_attr) {
    int wave = (blockIdx.x * blockDim.x + threadIdx.x) >> 6;
    int lane = threadIdx.x & 63;
    if (wave >= N_NODES) return;
    int beg = rowptr[wave], end = rowptr[wave + 1];
    float s0 = 0.f, s1 = 0.f;
    int cnt = 0;
    for (int p = beg; p < end; ++p) {
        int e = eidx[p];
        if (e >= E_EDGES) continue;   // skip self loop
        ++cnt;
        s0 += ea[e * 128 + lane];
        s1 += ea[e * 128 + 64 + lane];
    }
    float inv = 1.f / fmaxf((float)cnt, 1.f);
    loop_attr[wave * 128 + lane] = s0 * inv;
    loop_attr[wave * 128 + 64 + lane] = s1 * inv;
}

// ---------------- K5: fp32 tiled GEMM  C[M,512] = A[M,128] @ B[128,512] ----------------
__global__ void k3_gemm(const float* __restrict__ A, const float* __restrict__ B,
                        float* __restrict__ C, int M) {
    __shared__ float As[16][64 + 1];
    __shared__ float Bs[16][64 + 1];
    int row0 = blockIdx.x * 64, col0 = blockIdx.y * 64;
    int t = threadIdx.x;
    int tx = t & 15, ty = t >> 4;
    float acc[4][4] = {};
    for (int k0 = 0; k0 < 128; k0 += 16) {
        for (int i = 0; i < 4; ++i) {
            int idx = t * 4 + i;
            int m = idx >> 4, k = idx & 15;
            int gr = row0 + m;
            As[k][m] = (gr < M) ? A[gr * 128 + k0 + k] : 0.f;
        }
        for (int i = 0; i < 4; ++i) {
            int idx = t * 4 + i;
            int k = idx >> 6, n = idx & 63;
            Bs[k][n] = B[(k0 + k) * 512 + col0 + n];
        }
        __syncthreads();
        for (int k = 0; k < 16; ++k) {
            float a[4], b[4];
            for (int i = 0; i < 4; ++i) a[i] = As[k][ty * 4 + i];
            for (int j = 0; j < 4; ++j) b[j] = Bs[k][tx * 4 + j];
            for (int i = 0; i < 4; ++i)
                for (int j = 0; j < 4; ++j) acc[i][j] += a[i] * b[j];
        }
        __syncthreads();
    }
    for (int i = 0; i < 4; ++i) {
        int gr = row0 + ty * 4 + i;
        if (gr < M)
            for (int j = 0; j < 4; ++j) C[gr * 512 + col0 + tx * 4 + j] = acc[i][j];
    }
}

// ---------------- K6: edge GEMM fused with GATv2 scoring -> logits[M_TOT, 8] ----------------
__global__ void k4_logits(const int* __restrict__ ei, const float* __restrict__ ea,
                          const float* __restrict__ loop_attr,
                          const float* __restrict__ xl, const float* __restrict__ xr,
                          const float* __restrict__ We, const float* __restrict__ att,
                          float* __restrict__ logits) {
    __shared__ float Ea[64][IN_CH + 1];
    __shared__ float Bs[16][64 + 1];
    __shared__ int s_src[64], s_dst[64];
    int row0 = blockIdx.x * 64;
    int t = threadIdx.x;

    if (t < 64) {
        int ge = row0 + t;
        int s = 0, d = 0;
        if (ge < E_EDGES) { s = ei[ge]; d = ei[E_EDGES + ge]; }
        else if (ge < M_TOT) { s = d = ge - E_EDGES; }
        s_src[t] = s; s_dst[t] = d;
    }
    for (int i = 0; i < 32; ++i) {
        int idx = t + i * 256;
        int r = idx >> 7, c = idx & 127;
        int ge = row0 + r;
        float v = 0.f;
        if (ge < E_EDGES) v = ea[ge * 128 + c];
        else if (ge < M_TOT) v = loop_attr[(ge - E_EDGES) * 128 + c];
        Ea[r][c] = v;
    }
    __syncthreads();

    int tx = t & 15, ty = t >> 4;
    for (int h = 0; h < H_HEADS; ++h) {
        float acc[4][4] = {};
        for (int k0 = 0; k0 < 128; k0 += 16) {
            for (int i = 0; i < 4; ++i) {
                int idx = t * 4 + i;
                int k = idx >> 6, n = idx & 63;
                Bs[k][n] = We[(k0 + k) * 512 + h * 64 + n];
            }
            __syncthreads();
            for (int k = 0; k < 16; ++k) {
                float a[4], b[4];
                for (int i = 0; i < 4; ++i) a[i] = Ea[ty * 4 + i][k0 + k];
                for (int j = 0; j < 4; ++j) b[j] = Bs[k][tx * 4 + j];
                for (int i = 0; i < 4; ++i)
                    for (int j = 0; j < 4; ++j) acc[i][j] += a[i] * b[j];
            }
            __syncthreads();
        }
        float part[4];
        for (int i = 0; i < 4; ++i) {
            int r = ty * 4 + i;
            int s = s_src[r], d = s_dst[r];
            float sum = 0.f;
            for (int j = 0; j < 4; ++j) {
                int c = tx * 4 + j;
                float v = acc[i][j] + xl[s * 512 + h * 64 + c] + xr[d * 512 + h * 64 + c];
                v = (v > 0.f) ? v : v * NEG_SLOPE;
                sum += att[h * 64 + c] * v;
            }
            part[i] = sum;
        }
        for (int m = 1; m < 16; m <<= 1)
            for (int i = 0; i < 4; ++i) part[i] += __shfl_xor(part[i], m, 64);
        if (tx == 0) {
            for (int i = 0; i < 4; ++i) {
                int ge = row0 + ty * 4 + i;
                if (ge < M_TOT) logits[ge * 8 + h] = part[i];
            }
        }
    }
}

// ---------------- K7: fused segment softmax + gather aggregation (one wave per node) ----------------
__global__ void k_agg(const int* __restrict__ rowptr, const int* __restrict__ eidx,
                      const int* __restrict__ ei, const float* __restrict__ logits,
                      const float* __restrict__ xl, const float* __restrict__ bias,
                      float* __restrict__ out) {
    int node = (blockIdx.x * blockDim.x + threadIdx.x) >> 6;
    int lane = threadIdx.x & 63;
    if (node >= N_NODES) return;
    int beg = rowptr[node], end = rowptr[node + 1];
    int h = lane >> 3;   // lane covers channels [lane*8, lane*8+8) -> head = lane/8

    // pass 1: per-head max (8 lanes per head compute redundantly)
    float m = -3.4e38f;
    for (int p = beg; p < end; ++p) {
        int e = eidx[p];
        m = fmaxf(m, logits[e * 8 + h]);
    }
    // pass 2: denom
    float den = 0.f;
    for (int p = beg; p < end; ++p) {
        int e = eidx[p];
        den += __expf(logits[e * 8 + h] - m);
    }
    float rden = 1.f / den;

    // pass 3: weighted gather
    float acc[8] = {};
    for (int p = beg; p < end; ++p) {
        int e = eidx[p];
        int s = (e < E_EDGES) ? ei[e] : e - E_EDGES;
        float alpha = __expf(logits[e * 8 + h] - m) * rden;
        const float4* xs = (const float4*)(xl + (size_t)s * 512 + lane * 8);
        float4 a = xs[0], b = xs[1];
        acc[0] += alpha * a.x; acc[1] += alpha * a.y;
        acc[2] += alpha * a.z; acc[3] += alpha * a.w;
        acc[4] += alpha * b.x; acc[5] += alpha * b.y;
        acc[6] += alpha * b.z; acc[7] += alpha * b.w;
    }
    float4* op = (float4*)(out + (size_t)node * 512 + lane * 8);
    const float4* bp = (const float4*)(bias + lane * 8);
    float4 b0 = bp[0], b1 = bp[1];
    float4 r0 = { acc[0] + b0.x, acc[1] + b0.y, acc[2] + b0.z, acc[3] + b0.w };
    float4 r1 = { acc[4] + b1.x, acc[5] + b1.y, acc[6] + b1.z, acc[7] + b1.w };
    op[0] = r0; op[1] = r1;
}

extern "C" void kernel_launch(void* const* d_in, const int* in_sizes, int n_in,
                              void* d_out, int out_size, void* d_ws, size_t ws_size,
                              hipStream_t stream) {
    const float* x    = (const float*)d_in[0];
    const int*   ei   = (const int*)d_in[1];
    const float* ea   = (const float*)d_in[2];
    const float* Wl   = (const float*)d_in[3];
    const float* Wr   = (const float*)d_in[4];
    const float* We   = (const float*)d_in[5];
    const float* att  = (const float*)d_in[6];
    const float* bias = (const float*)d_in[7];
    float* out = (float*)d_out;

    float* xl        = (float*)d_ws;                          // N*512
    float* xr        = xl + (size_t)N_NODES * HC;             // N*512
    float* loop_attr = xr + (size_t)N_NODES * HC;             // N*128
    float* logits    = loop_attr + (size_t)N_NODES * IN_CH;   // M_TOT*8
    int* deg         = (int*)(logits + (size_t)M_TOT * 8);    // N
    int* rowptr      = deg + N_NODES;                         // N+1
    int* cursor      = rowptr + N_NODES + 1;                  // N
    int* eidx        = cursor + N_NODES;                      // M_TOT

    const int B = 256;
    k_zero<<<(N_NODES + B - 1) / B, B, 0, stream>>>(deg);
    k_deg<<<(E_EDGES + B - 1) / B, B, 0, stream>>>(ei, deg);
    k_scan<<<1, B, 0, stream>>>(deg, rowptr, cursor, eidx);
    k_fill<<<(E_EDGES + B - 1) / B, B, 0, stream>>>(ei, cursor, eidx);
    k_loop_attr<<<(N_NODES * 64 + B - 1) / B, B, 0, stream>>>(rowptr, eidx, ea, loop_attr);
    k3_gemm<<<dim3((N_NODES + 63) / 64, 8), B, 0, stream>>>(x, Wl, xl, N_NODES);
    k3_gemm<<<dim3((N_NODES + 63) / 64, 8), B, 0, stream>>>(x, Wr, xr, N_NODES);
    k4_logits<<<(M_TOT + 63) / 64, B, 0, stream>>>(ei, ea, loop_attr, xl, xr, We, att, logits);
    k_agg<<<((size_t)N_NODES * 64 + B - 1) / B, B, 0, stream>>>(rowptr, eidx, ei, logits, xl, bias, out);
}

// Round 3
// 453.999 us; speedup vs baseline: 7.1534x; 1.8334x over previous
//
#include <hip/hip_runtime.h>

#define N_NODES 20000
#define E_EDGES 160000
#define IN_CH 128
#define H_HEADS 8
#define C_CH 64
#define HC 512
#define M_TOT (E_EDGES + N_NODES)
#define NEG_SLOPE 0.2f

typedef __attribute__((ext_vector_type(8))) short bf16x8;
typedef __attribute__((ext_vector_type(4))) float f32x4;

__device__ __forceinline__ unsigned short f2bf(float f) {
    unsigned u = __float_as_uint(f);
    unsigned r = (u + 0x7FFFu + ((u >> 16) & 1u)) >> 16;   // RNE
    return (unsigned short)r;
}

// ---------------- CSR build ----------------
__global__ void k_zero(int* __restrict__ deg) {
    int i = blockIdx.x * blockDim.x + threadIdx.x;
    if (i < N_NODES) deg[i] = 0;
}

__global__ void k_deg(const int* __restrict__ ei, int* __restrict__ deg) {
    int e = blockIdx.x * blockDim.x + threadIdx.x;
    if (e >= E_EDGES) return;
    atomicAdd(&deg[ei[E_EDGES + e]], 1);
}

__global__ void k_scan(const int* __restrict__ deg, int* __restrict__ rowptr,
                       int* __restrict__ cursor, int* __restrict__ eidx) {
    __shared__ int buf[256];
    __shared__ int carry;
    int tid = threadIdx.x;
    if (tid == 0) carry = 0;
    __syncthreads();
    for (int base = 0; base < N_NODES; base += 256) {
        int i = base + tid;
        int v = (i < N_NODES) ? (deg[i] + 1) : 0;   // +1 = self loop
        buf[tid] = v;
        __syncthreads();
        for (int off = 1; off < 256; off <<= 1) {
            int t = (tid >= off) ? buf[tid - off] : 0;
            __syncthreads();
            buf[tid] += t;
            __syncthreads();
        }
        int c = carry;
        int incl = buf[tid] + c;
        int excl = incl - v;
        if (i < N_NODES) {
            rowptr[i] = excl;
            eidx[excl] = E_EDGES + i;   // self-loop edge in slot 0
            cursor[i] = excl + 1;
        }
        __syncthreads();
        if (tid == 0) carry = c + buf[255];
        __syncthreads();
    }
    if (tid == 0) rowptr[N_NODES] = carry;
}

__global__ void k_fill(const int* __restrict__ ei, int* __restrict__ cursor,
                       int* __restrict__ eidx) {
    int e = blockIdx.x * blockDim.x + threadIdx.x;
    if (e >= E_EDGES) return;
    int slot = atomicAdd(&cursor[ei[E_EDGES + e]], 1);
    eidx[slot] = e;
}

// ---------------- loop_attr = mean of incoming edge_attr ----------------
__global__ void k_loop_attr(const int* __restrict__ rowptr, const int* __restrict__ eidx,
                            const float* __restrict__ ea, float* __restrict__ loop_attr) {
    int wave = (blockIdx.x * blockDim.x + threadIdx.x) >> 6;
    int lane = threadIdx.x & 63;
    if (wave >= N_NODES) return;
    int beg = rowptr[wave], end = rowptr[wave + 1];
    float s0 = 0.f, s1 = 0.f;
    int cnt = 0;
    for (int p = beg; p < end; ++p) {
        int e = eidx[p];
        if (e >= E_EDGES) continue;
        ++cnt;
        s0 += ea[(size_t)e * 128 + lane];
        s1 += ea[(size_t)e * 128 + 64 + lane];
    }
    float inv = 1.f / fmaxf((float)cnt, 1.f);
    loop_attr[(size_t)wave * 128 + lane] = s0 * inv;
    loop_attr[(size_t)wave * 128 + 64 + lane] = s1 * inv;
}

// ---------------- weight transpose + bf16: WT[n][k] = bf16(W[k][n]) ----------------
__global__ void k_trans(const float* __restrict__ W, unsigned short* __restrict__ WT) {
    int idx = blockIdx.x * blockDim.x + threadIdx.x;
    if (idx >= HC * IN_CH) return;
    int n = idx >> 7, k = idx & 127;
    WT[idx] = f2bf(W[(size_t)k * HC + n]);
}

// ---------------- MFMA GEMM: C[M,512] = A[M,128] @ WT^T, fp32 out ----------------
__global__ void k_gemm_mfma(const float* __restrict__ A, const unsigned short* __restrict__ BT,
                            float* __restrict__ C, int M) {
    __shared__ short As[64 * 128];
    int row0 = blockIdx.x * 64;
    int t = threadIdx.x;
    // stage + convert + swizzle
    {
        int row = t >> 2, c0 = (t & 3) * 32;
        int gr = row0 + row;
        int sw = (row & 7) << 4;
        const float* src = A + (size_t)gr * 128 + c0;
        #pragma unroll
        for (int i = 0; i < 4; ++i) {
            bf16x8 v;
            if (gr < M) {
                const float4* p = (const float4*)(src + i * 8);
                float4 f0 = p[0], f1 = p[1];
                v[0] = f2bf(f0.x); v[1] = f2bf(f0.y); v[2] = f2bf(f0.z); v[3] = f2bf(f0.w);
                v[4] = f2bf(f1.x); v[5] = f2bf(f1.y); v[6] = f2bf(f1.z); v[7] = f2bf(f1.w);
            } else {
                #pragma unroll
                for (int j = 0; j < 8; ++j) v[j] = 0;
            }
            int off = row * 256 + (((c0 + i * 8) * 2) ^ sw);
            *(bf16x8*)((char*)As + off) = v;
        }
    }
    __syncthreads();

    int w = t >> 6, l = t & 63;
    int lr = l & 15, lk = l >> 4;
    int col0 = blockIdx.y * 256 + w * 64;

    f32x4 acc[4][4];
    #pragma unroll
    for (int mi = 0; mi < 4; ++mi)
        #pragma unroll
        for (int fj = 0; fj < 4; ++fj)
            #pragma unroll
            for (int q = 0; q < 4; ++q) acc[mi][fj][q] = 0.f;

    #pragma unroll
    for (int k0 = 0; k0 < 4; ++k0) {
        bf16x8 a4[4];
        #pragma unroll
        for (int mi = 0; mi < 4; ++mi) {
            int row = mi * 16 + lr;
            int off = row * 256 + ((k0 * 64 + lk * 16) ^ ((row & 7) << 4));
            a4[mi] = *(const bf16x8*)((const char*)As + off);
        }
        #pragma unroll
        for (int fj = 0; fj < 4; ++fj) {
            bf16x8 b = *(const bf16x8*)(BT + (size_t)(col0 + fj * 16 + lr) * 128 + k0 * 32 + lk * 8);
            #pragma unroll
            for (int mi = 0; mi < 4; ++mi)
                acc[mi][fj] = __builtin_amdgcn_mfma_f32_16x16x32_bf16(a4[mi], b, acc[mi][fj], 0, 0, 0);
        }
    }
    #pragma unroll
    for (int mi = 0; mi < 4; ++mi) {
        #pragma unroll
        for (int reg = 0; reg < 4; ++reg) {
            int r = row0 + mi * 16 + lk * 4 + reg;
            if (r < M) {
                float* cp = C + (size_t)r * 512 + col0 + lr;
                #pragma unroll
                for (int fj = 0; fj < 4; ++fj) cp[fj * 16] = acc[mi][fj][reg];
            }
        }
    }
}

// ---------------- MFMA edge GEMM fused with GATv2 scoring ----------------
__global__ void k_logits_mfma(const int* __restrict__ ei, const float* __restrict__ ea,
                              const float* __restrict__ loop_attr,
                              const unsigned short* __restrict__ WeT,
                              const float* __restrict__ xl, const float* __restrict__ xr,
                              const float* __restrict__ att, float* __restrict__ logits) {
    __shared__ short As[64 * 128];
    __shared__ int s_src[64], s_dst[64];
    int row0 = blockIdx.x * 64;
    int t = threadIdx.x;

    if (t < 64) {
        int ge = row0 + t;
        int s = 0, d = 0;
        if (ge < E_EDGES) { s = ei[ge]; d = ei[E_EDGES + ge]; }
        else if (ge < M_TOT) { s = d = ge - E_EDGES; }
        s_src[t] = s; s_dst[t] = d;
    }
    {
        int row = t >> 2, c0 = (t & 3) * 32;
        int ge = row0 + row;
        int sw = (row & 7) << 4;
        const float* src = nullptr;
        if (ge < E_EDGES) src = ea + (size_t)ge * 128 + c0;
        else if (ge < M_TOT) src = loop_attr + (size_t)(ge - E_EDGES) * 128 + c0;
        #pragma unroll
        for (int i = 0; i < 4; ++i) {
            bf16x8 v;
            if (src) {
                const float4* p = (const float4*)(src + i * 8);
                float4 f0 = p[0], f1 = p[1];
                v[0] = f2bf(f0.x); v[1] = f2bf(f0.y); v[2] = f2bf(f0.z); v[3] = f2bf(f0.w);
                v[4] = f2bf(f1.x); v[5] = f2bf(f1.y); v[6] = f2bf(f1.z); v[7] = f2bf(f1.w);
            } else {
                #pragma unroll
                for (int j = 0; j < 8; ++j) v[j] = 0;
            }
            int off = row * 256 + (((c0 + i * 8) * 2) ^ sw);
            *(bf16x8*)((char*)As + off) = v;
        }
    }
    __syncthreads();

    int w = t >> 6, l = t & 63;
    int lr = l & 15, lk = l >> 4;

    #pragma unroll
    for (int hh = 0; hh < 2; ++hh) {
        int h = w * 2 + hh;
        int cb = h * 64;

        f32x4 acc[4][4];
        #pragma unroll
        for (int mi = 0; mi < 4; ++mi)
            #pragma unroll
            for (int fj = 0; fj < 4; ++fj)
                #pragma unroll
                for (int q = 0; q < 4; ++q) acc[mi][fj][q] = 0.f;

        #pragma unroll
        for (int k0 = 0; k0 < 4; ++k0) {
            bf16x8 a4[4];
            #pragma unroll
            for (int mi = 0; mi < 4; ++mi) {
                int row = mi * 16 + lr;
                int off = row * 256 + ((k0 * 64 + lk * 16) ^ ((row & 7) << 4));
                a4[mi] = *(const bf16x8*)((const char*)As + off);
            }
            #pragma unroll
            for (int fj = 0; fj < 4; ++fj) {
                bf16x8 b = *(const bf16x8*)(WeT + (size_t)(cb + fj * 16 + lr) * 128 + k0 * 32 + lk * 8);
                #pragma unroll
                for (int mi = 0; mi < 4; ++mi)
                    acc[mi][fj] = __builtin_amdgcn_mfma_f32_16x16x32_bf16(a4[mi], b, acc[mi][fj], 0, 0, 0);
            }
        }

        float attv[4];
        #pragma unroll
        for (int fj = 0; fj < 4; ++fj) attv[fj] = att[cb + fj * 16 + lr];

        #pragma unroll
        for (int mi = 0; mi < 4; ++mi) {
            #pragma unroll
            for (int reg = 0; reg < 4; ++reg) {
                int r = mi * 16 + lk * 4 + reg;
                int s = s_src[r], d = s_dst[r];
                const float* xlp = xl + (size_t)s * 512 + cb + lr;
                const float* xrp = xr + (size_t)d * 512 + cb + lr;
                float sum = 0.f;
                #pragma unroll
                for (int fj = 0; fj < 4; ++fj) {
                    float v = acc[mi][fj][reg] + xlp[fj * 16] + xrp[fj * 16];
                    v = (v > 0.f) ? v : v * NEG_SLOPE;
                    sum = fmaf(attv[fj], v, sum);
                }
                sum += __shfl_xor(sum, 1, 64);
                sum += __shfl_xor(sum, 2, 64);
                sum += __shfl_xor(sum, 4, 64);
                sum += __shfl_xor(sum, 8, 64);
                if (lr == 0) {
                    int ge = row0 + r;
                    if (ge < M_TOT) logits[(size_t)ge * 8 + h] = sum;
                }
            }
        }
    }
}

// ---------------- fused segment softmax + gather aggregation ----------------
__global__ void k_agg(const int* __restrict__ rowptr, const int* __restrict__ eidx,
                      const int* __restrict__ ei, const float* __restrict__ logits,
                      const float* __restrict__ xl, const float* __restrict__ bias,
                      float* __restrict__ out) {
    int node = (blockIdx.x * blockDim.x + threadIdx.x) >> 6;
    int lane = threadIdx.x & 63;
    if (node >= N_NODES) return;
    int beg = rowptr[node], end = rowptr[node + 1];
    int h = lane >> 3;

    float m = -3.4e38f;
    for (int p = beg; p < end; ++p) {
        int e = eidx[p];
        m = fmaxf(m, logits[(size_t)e * 8 + h]);
    }
    float den = 0.f;
    for (int p = beg; p < end; ++p) {
        int e = eidx[p];
        den += __expf(logits[(size_t)e * 8 + h] - m);
    }
    float rden = 1.f / den;

    float acc[8] = {};
    for (int p = beg; p < end; ++p) {
        int e = eidx[p];
        int s = (e < E_EDGES) ? ei[e] : e - E_EDGES;
        float alpha = __expf(logits[(size_t)e * 8 + h] - m) * rden;
        const float4* xs = (const float4*)(xl + (size_t)s * 512 + lane * 8);
        float4 a = xs[0], b = xs[1];
        acc[0] += alpha * a.x; acc[1] += alpha * a.y;
        acc[2] += alpha * a.z; acc[3] += alpha * a.w;
        acc[4] += alpha * b.x; acc[5] += alpha * b.y;
        acc[6] += alpha * b.z; acc[7] += alpha * b.w;
    }
    float4* op = (float4*)(out + (size_t)node * 512 + lane * 8);
    const float4* bp = (const float4*)(bias + lane * 8);
    float4 b0 = bp[0], b1 = bp[1];
    float4 r0 = { acc[0] + b0.x, acc[1] + b0.y, acc[2] + b0.z, acc[3] + b0.w };
    float4 r1 = { acc[4] + b1.x, acc[5] + b1.y, acc[6] + b1.z, acc[7] + b1.w };
    op[0] = r0; op[1] = r1;
}

extern "C" void kernel_launch(void* const* d_in, const int* in_sizes, int n_in,
                              void* d_out, int out_size, void* d_ws, size_t ws_size,
                              hipStream_t stream) {
    const float* x    = (const float*)d_in[0];
    const int*   ei   = (const int*)d_in[1];
    const float* ea   = (const float*)d_in[2];
    const float* Wl   = (const float*)d_in[3];
    const float* Wr   = (const float*)d_in[4];
    const float* We   = (const float*)d_in[5];
    const float* att  = (const float*)d_in[6];
    const float* bias = (const float*)d_in[7];
    float* out = (float*)d_out;

    float* xl        = (float*)d_ws;                          // N*512
    float* xr        = xl + (size_t)N_NODES * HC;             // N*512
    float* loop_attr = xr + (size_t)N_NODES * HC;             // N*128
    float* logits    = loop_attr + (size_t)N_NODES * IN_CH;   // M_TOT*8
    unsigned short* WlT = (unsigned short*)(logits + (size_t)M_TOT * 8); // 512*128
    unsigned short* WrT = WlT + HC * IN_CH;
    unsigned short* WeT = WrT + HC * IN_CH;
    int* deg         = (int*)(WeT + HC * IN_CH);
    int* rowptr      = deg + N_NODES;
    int* cursor      = rowptr + N_NODES + 1;
    int* eidx        = cursor + N_NODES;

    const int B = 256;
    k_zero<<<(N_NODES + B - 1) / B, B, 0, stream>>>(deg);
    k_deg<<<(E_EDGES + B - 1) / B, B, 0, stream>>>(ei, deg);
    k_scan<<<1, B, 0, stream>>>(deg, rowptr, cursor, eidx);
    k_fill<<<(E_EDGES + B - 1) / B, B, 0, stream>>>(ei, cursor, eidx);
    k_loop_attr<<<(N_NODES * 64 + B - 1) / B, B, 0, stream>>>(rowptr, eidx, ea, loop_attr);
    k_trans<<<(HC * IN_CH + B - 1) / B, B, 0, stream>>>(Wl, WlT);
    k_trans<<<(HC * IN_CH + B - 1) / B, B, 0, stream>>>(Wr, WrT);
    k_trans<<<(HC * IN_CH + B - 1) / B, B, 0, stream>>>(We, WeT);
    k_gemm_mfma<<<dim3((N_NODES + 63) / 64, 2), B, 0, stream>>>(x, WlT, xl, N_NODES);
    k_gemm_mfma<<<dim3((N_NODES + 63) / 64, 2), B, 0, stream>>>(x, WrT, xr, N_NODES);
    k_logits_mfma<<<(M_TOT + 63) / 64, B, 0, stream>>>(ei, ea, loop_attr, WeT, xl, xr, att, logits);
    k_agg<<<((size_t)N_NODES * 64 + B - 1) / B, B, 0, stream>>>(rowptr, eidx, ei, logits, xl, bias, out);
}

// Round 4
// 355.870 us; speedup vs baseline: 9.1259x; 1.2757x over previous
//
#include <hip/hip_runtime.h>

#define N_NODES 20000
#define E_EDGES 160000
#define IN_CH 128
#define H_HEADS 8
#define C_CH 64
#define HC 512
#define M_TOT (E_EDGES + N_NODES)
#define NEG_SLOPE 0.2f

typedef __attribute__((ext_vector_type(8))) short bf16x8;
typedef __attribute__((ext_vector_type(4))) float f32x4;

__device__ __forceinline__ unsigned short f2bf(float f) {
    unsigned u = __float_as_uint(f);
    unsigned r = (u + 0x7FFFu + ((u >> 16) & 1u)) >> 16;   // RNE
    return (unsigned short)r;
}
__device__ __forceinline__ float bf2f(unsigned short s) {
    return __uint_as_float((unsigned)s << 16);
}

// ---------------- CSR build ----------------
__global__ void k_zero(int* __restrict__ deg) {
    int i = blockIdx.x * blockDim.x + threadIdx.x;
    if (i < N_NODES) deg[i] = 0;
}

__global__ void k_deg(const int* __restrict__ ei, int* __restrict__ deg) {
    int e = blockIdx.x * blockDim.x + threadIdx.x;
    if (e >= E_EDGES) return;
    atomicAdd(&deg[ei[E_EDGES + e]], 1);
}

__global__ void k_scan(const int* __restrict__ deg, int* __restrict__ rowptr,
                       int* __restrict__ cursor, int* __restrict__ eidx) {
    __shared__ int buf[256];
    __shared__ int carry;
    int tid = threadIdx.x;
    if (tid == 0) carry = 0;
    __syncthreads();
    for (int base = 0; base < N_NODES; base += 256) {
        int i = base + tid;
        int v = (i < N_NODES) ? (deg[i] + 1) : 0;   // +1 = self loop
        buf[tid] = v;
        __syncthreads();
        for (int off = 1; off < 256; off <<= 1) {
            int t = (tid >= off) ? buf[tid - off] : 0;
            __syncthreads();
            buf[tid] += t;
            __syncthreads();
        }
        int c = carry;
        int incl = buf[tid] + c;
        int excl = incl - v;
        if (i < N_NODES) {
            rowptr[i] = excl;
            eidx[excl] = E_EDGES + i;   // self-loop edge in slot 0
            cursor[i] = excl + 1;
        }
        __syncthreads();
        if (tid == 0) carry = c + buf[255];
        __syncthreads();
    }
    if (tid == 0) rowptr[N_NODES] = carry;
}

__global__ void k_fill(const int* __restrict__ ei, int* __restrict__ cursor,
                       int* __restrict__ eidx) {
    int e = blockIdx.x * blockDim.x + threadIdx.x;
    if (e >= E_EDGES) return;
    int slot = atomicAdd(&cursor[ei[E_EDGES + e]], 1);
    eidx[slot] = e;
}

// ---------------- loop_attr = mean of incoming edge_attr ----------------
__global__ void k_loop_attr(const int* __restrict__ rowptr, const int* __restrict__ eidx,
                            const float* __restrict__ ea, float* __restrict__ loop_attr) {
    int wave = (blockIdx.x * blockDim.x + threadIdx.x) >> 6;
    int lane = threadIdx.x & 63;
    if (wave >= N_NODES) return;
    int beg = rowptr[wave], end = rowptr[wave + 1];
    float s0 = 0.f, s1 = 0.f;
    int cnt = 0;
    for (int p = beg; p < end; ++p) {
        int e = eidx[p];
        if (e >= E_EDGES) continue;
        ++cnt;
        s0 += ea[(size_t)e * 128 + lane];
        s1 += ea[(size_t)e * 128 + 64 + lane];
    }
    float inv = 1.f / fmaxf((float)cnt, 1.f);
    loop_attr[(size_t)wave * 128 + lane] = s0 * inv;
    loop_attr[(size_t)wave * 128 + 64 + lane] = s1 * inv;
}

// ---------------- weight transpose + bf16: WT[n][k] = bf16(W[k][n]) ----------------
__global__ void k_trans(const float* __restrict__ W, unsigned short* __restrict__ WT) {
    int idx = blockIdx.x * blockDim.x + threadIdx.x;
    if (idx >= HC * IN_CH) return;
    int n = idx >> 7, k = idx & 127;
    WT[idx] = f2bf(W[(size_t)k * HC + n]);
}

// ---------------- MFMA GEMM: Cb[M,512] = bf16(A[M,128] @ WT^T) ----------------
__global__ void k_gemm_mfma(const float* __restrict__ A, const unsigned short* __restrict__ BT,
                            unsigned short* __restrict__ Cb, int M) {
    __shared__ short As[64 * 128];
    int row0 = blockIdx.x * 64;
    int t = threadIdx.x;
    {
        int row = t >> 2, c0 = (t & 3) * 32;
        int gr = row0 + row;
        int sw = (row & 7) << 4;
        const float* src = A + (size_t)gr * 128 + c0;
        #pragma unroll
        for (int i = 0; i < 4; ++i) {
            bf16x8 v;
            if (gr < M) {
                const float4* p = (const float4*)(src + i * 8);
                float4 f0 = p[0], f1 = p[1];
                v[0] = f2bf(f0.x); v[1] = f2bf(f0.y); v[2] = f2bf(f0.z); v[3] = f2bf(f0.w);
                v[4] = f2bf(f1.x); v[5] = f2bf(f1.y); v[6] = f2bf(f1.z); v[7] = f2bf(f1.w);
            } else {
                #pragma unroll
                for (int j = 0; j < 8; ++j) v[j] = 0;
            }
            int off = row * 256 + (((c0 + i * 8) * 2) ^ sw);
            *(bf16x8*)((char*)As + off) = v;
        }
    }
    __syncthreads();

    int w = t >> 6, l = t & 63;
    int lr = l & 15, lk = l >> 4;
    int col0 = blockIdx.y * 256 + w * 64;

    f32x4 acc[4][4];
    #pragma unroll
    for (int mi = 0; mi < 4; ++mi)
        #pragma unroll
        for (int fj = 0; fj < 4; ++fj)
            #pragma unroll
            for (int q = 0; q < 4; ++q) acc[mi][fj][q] = 0.f;

    #pragma unroll
    for (int k0 = 0; k0 < 4; ++k0) {
        bf16x8 a4[4];
        #pragma unroll
        for (int mi = 0; mi < 4; ++mi) {
            int row = mi * 16 + lr;
            int off = row * 256 + ((k0 * 64 + lk * 16) ^ ((row & 7) << 4));
            a4[mi] = *(const bf16x8*)((const char*)As + off);
        }
        #pragma unroll
        for (int fj = 0; fj < 4; ++fj) {
            bf16x8 b = *(const bf16x8*)(BT + (size_t)(col0 + fj * 16 + lr) * 128 + k0 * 32 + lk * 8);
            #pragma unroll
            for (int mi = 0; mi < 4; ++mi)
                acc[mi][fj] = __builtin_amdgcn_mfma_f32_16x16x32_bf16(a4[mi], b, acc[mi][fj], 0, 0, 0);
        }
    }
    #pragma unroll
    for (int mi = 0; mi < 4; ++mi) {
        #pragma unroll
        for (int reg = 0; reg < 4; ++reg) {
            int r = row0 + mi * 16 + lk * 4 + reg;
            if (r < M) {
                unsigned short* cp = Cb + (size_t)r * 512 + col0 + lr;
                #pragma unroll
                for (int fj = 0; fj < 4; ++fj) cp[fj * 16] = f2bf(acc[mi][fj][reg]);
            }
        }
    }
}

// ---------------- MFMA edge GEMM fused with GATv2 scoring ----------------
// Epilogue: per-wave LDS transpose of xe so each lane owns 16 contiguous
// channels of one edge -> xl/xr gathers become 2x16B vector loads.
// Relies on same-wave LDS op ordering (per-wave DS FIFO) - no barrier needed.
__global__ void k_logits_mfma(const int* __restrict__ ei, const float* __restrict__ ea,
                              const float* __restrict__ loop_attr,
                              const unsigned short* __restrict__ WeT,
                              const unsigned short* __restrict__ xlb,
                              const unsigned short* __restrict__ xrb,
                              const float* __restrict__ att, float* __restrict__ logits) {
    __shared__ short As[64 * 128];
    __shared__ float xeT[4][16][68];
    __shared__ float att_s[512];
    __shared__ int s_src[64], s_dst[64];
    int row0 = blockIdx.x * 64;
    int t = threadIdx.x;

    if (t < 64) {
        int ge = row0 + t;
        int s = 0, d = 0;
        if (ge < E_EDGES) { s = ei[ge]; d = ei[E_EDGES + ge]; }
        else if (ge < M_TOT) { s = d = ge - E_EDGES; }
        s_src[t] = s; s_dst[t] = d;
    }
    att_s[t] = att[t];
    att_s[t + 256] = att[t + 256];
    {
        int row = t >> 2, c0 = (t & 3) * 32;
        int ge = row0 + row;
        int sw = (row & 7) << 4;
        const float* src = nullptr;
        if (ge < E_EDGES) src = ea + (size_t)ge * 128 + c0;
        else if (ge < M_TOT) src = loop_attr + (size_t)(ge - E_EDGES) * 128 + c0;
        #pragma unroll
        for (int i = 0; i < 4; ++i) {
            bf16x8 v;
            if (src) {
                const float4* p = (const float4*)(src + i * 8);
                float4 f0 = p[0], f1 = p[1];
                v[0] = f2bf(f0.x); v[1] = f2bf(f0.y); v[2] = f2bf(f0.z); v[3] = f2bf(f0.w);
                v[4] = f2bf(f1.x); v[5] = f2bf(f1.y); v[6] = f2bf(f1.z); v[7] = f2bf(f1.w);
            } else {
                #pragma unroll
                for (int j = 0; j < 8; ++j) v[j] = 0;
            }
            int off = row * 256 + (((c0 + i * 8) * 2) ^ sw);
            *(bf16x8*)((char*)As + off) = v;
        }
    }
    __syncthreads();

    int w = t >> 6, l = t & 63;
    int lr = l & 15, lk = l >> 4;
    int eloc = l >> 2, q = l & 3;   // epilogue roles: 4 lanes per edge

    #pragma unroll
    for (int hh = 0; hh < 2; ++hh) {
        int h = w * 2 + hh;
        int cb = h * 64;

        f32x4 acc[4][4];
        #pragma unroll
        for (int mi = 0; mi < 4; ++mi)
            #pragma unroll
            for (int fj = 0; fj < 4; ++fj)
                #pragma unroll
                for (int qq = 0; qq < 4; ++qq) acc[mi][fj][qq] = 0.f;

        #pragma unroll
        for (int k0 = 0; k0 < 4; ++k0) {
            bf16x8 a4[4];
            #pragma unroll
            for (int mi = 0; mi < 4; ++mi) {
                int row = mi * 16 + lr;
                int off = row * 256 + ((k0 * 64 + lk * 16) ^ ((row & 7) << 4));
                a4[mi] = *(const bf16x8*)((const char*)As + off);
            }
            #pragma unroll
            for (int fj = 0; fj < 4; ++fj) {
                bf16x8 b = *(const bf16x8*)(WeT + (size_t)(cb + fj * 16 + lr) * 128 + k0 * 32 + lk * 8);
                #pragma unroll
                for (int mi = 0; mi < 4; ++mi)
                    acc[mi][fj] = __builtin_amdgcn_mfma_f32_16x16x32_bf16(a4[mi], b, acc[mi][fj], 0, 0, 0);
            }
        }

        #pragma unroll
        for (int mi = 0; mi < 4; ++mi) {
            // transpose xe tile (16 edges x 64 ch) through wave-private LDS
            #pragma unroll
            for (int fj = 0; fj < 4; ++fj)
                #pragma unroll
                for (int reg = 0; reg < 4; ++reg)
                    xeT[w][lk * 4 + reg][fj * 16 + lr] = acc[mi][fj][reg];

            int r = mi * 16 + eloc;
            int s = s_src[r], d = s_dst[r];
            const bf16x8* xlp = (const bf16x8*)(xlb + (size_t)s * 512 + cb + q * 16);
            const bf16x8* xrp = (const bf16x8*)(xrb + (size_t)d * 512 + cb + q * 16);
            bf16x8 a0 = xlp[0], a1 = xlp[1];
            bf16x8 b0 = xrp[0], b1 = xrp[1];

            float sum = 0.f;
            #pragma unroll
            for (int sg = 0; sg < 4; ++sg) {
                float4 xe4 = *(const float4*)&xeT[w][eloc][q * 16 + sg * 4];
                float4 av  = *(const float4*)&att_s[cb + q * 16 + sg * 4];
                float xv[4], rv[4];
                #pragma unroll
                for (int j = 0; j < 4; ++j) {
                    int idx = sg * 4 + j;
                    xv[j] = bf2f((unsigned short)((idx < 8) ? a0[idx] : a1[idx - 8]));
                    rv[j] = bf2f((unsigned short)((idx < 8) ? b0[idx] : b1[idx - 8]));
                }
                float v0 = xe4.x + xv[0] + rv[0]; v0 = (v0 > 0.f) ? v0 : v0 * NEG_SLOPE;
                float v1 = xe4.y + xv[1] + rv[1]; v1 = (v1 > 0.f) ? v1 : v1 * NEG_SLOPE;
                float v2 = xe4.z + xv[2] + rv[2]; v2 = (v2 > 0.f) ? v2 : v2 * NEG_SLOPE;
                float v3 = xe4.w + xv[3] + rv[3]; v3 = (v3 > 0.f) ? v3 : v3 * NEG_SLOPE;
                sum = fmaf(av.x, v0, sum);
                sum = fmaf(av.y, v1, sum);
                sum = fmaf(av.z, v2, sum);
                sum = fmaf(av.w, v3, sum);
            }
            sum += __shfl_xor(sum, 1, 64);
            sum += __shfl_xor(sum, 2, 64);
            if (q == 0) {
                int ge = row0 + r;
                if (ge < M_TOT) logits[(size_t)ge * 8 + h] = sum;
            }
        }
    }
}

// ---------------- fused segment softmax + gather aggregation ----------------
__global__ void k_agg(const int* __restrict__ rowptr, const int* __restrict__ eidx,
                      const int* __restrict__ ei, const float* __restrict__ logits,
                      const unsigned short* __restrict__ xlb, const float* __restrict__ bias,
                      float* __restrict__ out) {
    int node = (blockIdx.x * blockDim.x + threadIdx.x) >> 6;
    int lane = threadIdx.x & 63;
    if (node >= N_NODES) return;
    int beg = rowptr[node], end = rowptr[node + 1];
    int h = lane >> 3;

    float m = -3.4e38f;
    for (int p = beg; p < end; ++p) {
        int e = eidx[p];
        m = fmaxf(m, logits[(size_t)e * 8 + h]);
    }
    float den = 0.f;
    for (int p = beg; p < end; ++p) {
        int e = eidx[p];
        den += __expf(logits[(size_t)e * 8 + h] - m);
    }
    float rden = 1.f / den;

    float acc[8] = {};
    for (int p = beg; p < end; ++p) {
        int e = eidx[p];
        int s = (e < E_EDGES) ? ei[e] : e - E_EDGES;
        float alpha = __expf(logits[(size_t)e * 8 + h] - m) * rden;
        bf16x8 v = *(const bf16x8*)(xlb + (size_t)s * 512 + lane * 8);
        #pragma unroll
        for (int j = 0; j < 8; ++j) acc[j] = fmaf(alpha, bf2f((unsigned short)v[j]), acc[j]);
    }
    float4* op = (float4*)(out + (size_t)node * 512 + lane * 8);
    const float4* bp = (const float4*)(bias + lane * 8);
    float4 bv0 = bp[0], bv1 = bp[1];
    float4 r0 = { acc[0] + bv0.x, acc[1] + bv0.y, acc[2] + bv0.z, acc[3] + bv0.w };
    float4 r1 = { acc[4] + bv1.x, acc[5] + bv1.y, acc[6] + bv1.z, acc[7] + bv1.w };
    op[0] = r0; op[1] = r1;
}

extern "C" void kernel_launch(void* const* d_in, const int* in_sizes, int n_in,
                              void* d_out, int out_size, void* d_ws, size_t ws_size,
                              hipStream_t stream) {
    const float* x    = (const float*)d_in[0];
    const int*   ei   = (const int*)d_in[1];
    const float* ea   = (const float*)d_in[2];
    const float* Wl   = (const float*)d_in[3];
    const float* Wr   = (const float*)d_in[4];
    const float* We   = (const float*)d_in[5];
    const float* att  = (const float*)d_in[6];
    const float* bias = (const float*)d_in[7];
    float* out = (float*)d_out;

    unsigned short* xlb = (unsigned short*)d_ws;             // N*512 bf16
    unsigned short* xrb = xlb + (size_t)N_NODES * HC;        // N*512 bf16
    unsigned short* WlT = xrb + (size_t)N_NODES * HC;        // 512*128 bf16
    unsigned short* WrT = WlT + HC * IN_CH;
    unsigned short* WeT = WrT + HC * IN_CH;
    float* loop_attr = (float*)(WeT + HC * IN_CH);           // N*128 f32
    float* logits    = loop_attr + (size_t)N_NODES * IN_CH;  // M_TOT*8 f32
    int* deg         = (int*)(logits + (size_t)M_TOT * 8);
    int* rowptr      = deg + N_NODES;
    int* cursor      = rowptr + N_NODES + 1;
    int* eidx        = cursor + N_NODES;

    const int B = 256;
    k_zero<<<(N_NODES + B - 1) / B, B, 0, stream>>>(deg);
    k_deg<<<(E_EDGES + B - 1) / B, B, 0, stream>>>(ei, deg);
    k_scan<<<1, B, 0, stream>>>(deg, rowptr, cursor, eidx);
    k_fill<<<(E_EDGES + B - 1) / B, B, 0, stream>>>(ei, cursor, eidx);
    k_loop_attr<<<(N_NODES * 64 + B - 1) / B, B, 0, stream>>>(rowptr, eidx, ea, loop_attr);
    k_trans<<<(HC * IN_CH + B - 1) / B, B, 0, stream>>>(Wl, WlT);
    k_trans<<<(HC * IN_CH + B - 1) / B, B, 0, stream>>>(Wr, WrT);
    k_trans<<<(HC * IN_CH + B - 1) / B, B, 0, stream>>>(We, WeT);
    k_gemm_mfma<<<dim3((N_NODES + 63) / 64, 2), B, 0, stream>>>(x, WlT, xlb, N_NODES);
    k_gemm_mfma<<<dim3((N_NODES + 63) / 64, 2), B, 0, stream>>>(x, WrT, xrb, N_NODES);
    k_logits_mfma<<<(M_TOT + 63) / 64, B, 0, stream>>>(ei, ea, loop_attr, WeT, xlb, xrb, att, logits);
    k_agg<<<((size_t)N_NODES * 64 + B - 1) / B, B, 0, stream>>>(rowptr, eidx, ei, logits, xlb, bias, out);
}

// Round 5
// 347.652 us; speedup vs baseline: 9.3417x; 1.0236x over previous
//
#include <hip/hip_runtime.h>

#define N_NODES 20000
#define E_EDGES 160000
#define IN_CH 128
#define H_HEADS 8
#define C_CH 64
#define HC 512
#define M_TOT (E_EDGES + N_NODES)
#define NEG_SLOPE 0.2f

typedef __attribute__((ext_vector_type(8))) short bf16x8;
typedef __attribute__((ext_vector_type(4))) float f32x4;

__device__ __forceinline__ unsigned short f2bf(float f) {
    unsigned u = __float_as_uint(f);
    unsigned r = (u + 0x7FFFu + ((u >> 16) & 1u)) >> 16;   // RNE
    return (unsigned short)r;
}
__device__ __forceinline__ float bf2f(unsigned short s) {
    return __uint_as_float((unsigned)s << 16);
}
__device__ __forceinline__ float bfx(const bf16x8& v0, const bf16x8& v1, int idx) {
    return bf2f((unsigned short)((idx < 8) ? v0[idx] : v1[idx - 8]));
}

// ---------------- CSR build ----------------
__global__ void k_zero(int* __restrict__ deg) {
    int i = blockIdx.x * blockDim.x + threadIdx.x;
    if (i < N_NODES) deg[i] = 0;
}

__global__ void k_deg(const int* __restrict__ ei, int* __restrict__ deg) {
    int e = blockIdx.x * blockDim.x + threadIdx.x;
    if (e >= E_EDGES) return;
    atomicAdd(&deg[ei[E_EDGES + e]], 1);
}

__global__ void k_scan(const int* __restrict__ deg, int* __restrict__ rowptr,
                       int* __restrict__ cursor, int* __restrict__ eidx,
                       int* __restrict__ src_s, int* __restrict__ dst_s) {
    __shared__ int buf[256];
    __shared__ int carry;
    int tid = threadIdx.x;
    if (tid == 0) carry = 0;
    __syncthreads();
    for (int base = 0; base < N_NODES; base += 256) {
        int i = base + tid;
        int v = (i < N_NODES) ? (deg[i] + 1) : 0;   // +1 = self loop
        buf[tid] = v;
        __syncthreads();
        for (int off = 1; off < 256; off <<= 1) {
            int t = (tid >= off) ? buf[tid - off] : 0;
            __syncthreads();
            buf[tid] += t;
            __syncthreads();
        }
        int c = carry;
        int incl = buf[tid] + c;
        int excl = incl - v;
        if (i < N_NODES) {
            rowptr[i] = excl;
            eidx[excl] = E_EDGES + i;   // self-loop edge in slot 0
            src_s[excl] = i;
            dst_s[excl] = i;
            cursor[i] = excl + 1;
        }
        __syncthreads();
        if (tid == 0) carry = c + buf[255];
        __syncthreads();
    }
    if (tid == 0) rowptr[N_NODES] = carry;
}

__global__ void k_fill(const int* __restrict__ ei, int* __restrict__ cursor,
                       int* __restrict__ eidx, int* __restrict__ src_s,
                       int* __restrict__ dst_s) {
    int e = blockIdx.x * blockDim.x + threadIdx.x;
    if (e >= E_EDGES) return;
    int d = ei[E_EDGES + e];
    int slot = atomicAdd(&cursor[d], 1);
    eidx[slot] = e;
    src_s[slot] = ei[e];
    dst_s[slot] = d;
}

// ---------------- loop_attr = mean of incoming edge_attr (slot0 = self loop, skip) ----------------
__global__ void k_loop_attr(const int* __restrict__ rowptr, const int* __restrict__ eidx,
                            const float* __restrict__ ea, float* __restrict__ loop_attr) {
    int wave = (blockIdx.x * blockDim.x + threadIdx.x) >> 6;
    int lane = threadIdx.x & 63;
    if (wave >= N_NODES) return;
    int beg = rowptr[wave] + 1, end = rowptr[wave + 1];
    int cnt = end - beg;
    float s0 = 0.f, s1 = 0.f;
    if (beg < end) {
        int e_nxt = eidx[beg];
        const float* p_nxt = ea + (size_t)e_nxt * 128 + lane;
        for (int p = beg; p < end; ++p) {
            const float* cur = p_nxt;
            if (p + 1 < end) p_nxt = ea + (size_t)eidx[p + 1] * 128 + lane;
            s0 += cur[0];
            s1 += cur[64];
        }
    }
    float inv = 1.f / fmaxf((float)cnt, 1.f);
    loop_attr[(size_t)wave * 128 + lane] = s0 * inv;
    loop_attr[(size_t)wave * 128 + 64 + lane] = s1 * inv;
}

// ---------------- weight transpose + bf16: WT[n][k] = bf16(W[k][n]) ----------------
__global__ void k_trans(const float* __restrict__ W, unsigned short* __restrict__ WT) {
    int idx = blockIdx.x * blockDim.x + threadIdx.x;
    if (idx >= HC * IN_CH) return;
    int n = idx >> 7, k = idx & 127;
    WT[idx] = f2bf(W[(size_t)k * HC + n]);
}

// ---------------- merged dual MFMA GEMM: xlb = bf16(x@Wl), xrb = bf16(x@Wr) ----------------
__global__ void k_gemm2(const float* __restrict__ A,
                        const unsigned short* __restrict__ WlT,
                        const unsigned short* __restrict__ WrT,
                        unsigned short* __restrict__ xlb, unsigned short* __restrict__ xrb,
                        int M) {
    __shared__ short As[64 * 128];
    int row0 = blockIdx.x * 64;
    int sel = blockIdx.y >> 1;
    const unsigned short* BT = sel ? WrT : WlT;
    unsigned short* Cb = sel ? xrb : xlb;
    int t = threadIdx.x;
    {
        int row = t >> 2, c0 = (t & 3) * 32;
        int gr = row0 + row;
        int sw = (row & 7) << 4;
        const float* src = A + (size_t)gr * 128 + c0;
        #pragma unroll
        for (int i = 0; i < 4; ++i) {
            bf16x8 v;
            if (gr < M) {
                const float4* p = (const float4*)(src + i * 8);
                float4 f0 = p[0], f1 = p[1];
                v[0] = f2bf(f0.x); v[1] = f2bf(f0.y); v[2] = f2bf(f0.z); v[3] = f2bf(f0.w);
                v[4] = f2bf(f1.x); v[5] = f2bf(f1.y); v[6] = f2bf(f1.z); v[7] = f2bf(f1.w);
            } else {
                #pragma unroll
                for (int j = 0; j < 8; ++j) v[j] = 0;
            }
            int off = row * 256 + (((c0 + i * 8) * 2) ^ sw);
            *(bf16x8*)((char*)As + off) = v;
        }
    }
    __syncthreads();

    int w = t >> 6, l = t & 63;
    int lr = l & 15, lk = l >> 4;
    int col0 = (blockIdx.y & 1) * 256 + w * 64;

    f32x4 acc[4][4];
    #pragma unroll
    for (int mi = 0; mi < 4; ++mi)
        #pragma unroll
        for (int fj = 0; fj < 4; ++fj)
            #pragma unroll
            for (int q = 0; q < 4; ++q) acc[mi][fj][q] = 0.f;

    #pragma unroll
    for (int k0 = 0; k0 < 4; ++k0) {
        bf16x8 a4[4];
        #pragma unroll
        for (int mi = 0; mi < 4; ++mi) {
            int row = mi * 16 + lr;
            int off = row * 256 + ((k0 * 64 + lk * 16) ^ ((row & 7) << 4));
            a4[mi] = *(const bf16x8*)((const char*)As + off);
        }
        #pragma unroll
        for (int fj = 0; fj < 4; ++fj) {
            bf16x8 b = *(const bf16x8*)(BT + (size_t)(col0 + fj * 16 + lr) * 128 + k0 * 32 + lk * 8);
            #pragma unroll
            for (int mi = 0; mi < 4; ++mi)
                acc[mi][fj] = __builtin_amdgcn_mfma_f32_16x16x32_bf16(a4[mi], b, acc[mi][fj], 0, 0, 0);
        }
    }
    #pragma unroll
    for (int mi = 0; mi < 4; ++mi) {
        #pragma unroll
        for (int reg = 0; reg < 4; ++reg) {
            int r = row0 + mi * 16 + lk * 4 + reg;
            if (r < M) {
                unsigned short* cp = Cb + (size_t)r * 512 + col0 + lr;
                #pragma unroll
                for (int fj = 0; fj < 4; ++fj) cp[fj * 16] = f2bf(acc[mi][fj][reg]);
            }
        }
    }
}

// ---------------- MFMA edge GEMM (CSR order) fused with GATv2 scoring ----------------
#define PREF(R, CB, SLOT) { \
    int s_ = s_src[R], d_ = s_dst[R]; \
    const bf16x8* xp_ = (const bf16x8*)(xlb + (size_t)s_ * 512 + (CB) + q * 16); \
    pa0[SLOT] = xp_[0]; pa1[SLOT] = xp_[1]; \
    const bf16x8* rp_ = (const bf16x8*)(xrb + (size_t)d_ * 512 + (CB) + q * 16); \
    pb0[SLOT] = rp_[0]; pb1[SLOT] = rp_[1]; }

__global__ void k_logits_mfma(const int* __restrict__ eidx, const int* __restrict__ src_s,
                              const int* __restrict__ dst_s,
                              const float* __restrict__ ea, const float* __restrict__ loop_attr,
                              const unsigned short* __restrict__ WeT,
                              const unsigned short* __restrict__ xlb,
                              const unsigned short* __restrict__ xrb,
                              const float* __restrict__ att, float* __restrict__ logits) {
    __shared__ short As[64 * 128];
    __shared__ float xeT[4][16][68];
    __shared__ float att_s[512];
    __shared__ int s_src[64], s_dst[64];
    int row0 = blockIdx.x * 64;
    int t = threadIdx.x;

    if (t < 64) {
        int p = row0 + t;
        int s = 0, d = 0;
        if (p < M_TOT) { s = src_s[p]; d = dst_s[p]; }
        s_src[t] = s; s_dst[t] = d;
    }
    att_s[t] = att[t];
    att_s[t + 256] = att[t + 256];
    {
        int row = t >> 2, c0 = (t & 3) * 32;
        int p = row0 + row;
        int sw = (row & 7) << 4;
        const float* src = nullptr;
        if (p < M_TOT) {
            int e = eidx[p];
            src = (e < E_EDGES) ? ea + (size_t)e * 128 + c0
                                : loop_attr + (size_t)(e - E_EDGES) * 128 + c0;
        }
        #pragma unroll
        for (int i = 0; i < 4; ++i) {
            bf16x8 v;
            if (src) {
                const float4* p4 = (const float4*)(src + i * 8);
                float4 f0 = p4[0], f1 = p4[1];
                v[0] = f2bf(f0.x); v[1] = f2bf(f0.y); v[2] = f2bf(f0.z); v[3] = f2bf(f0.w);
                v[4] = f2bf(f1.x); v[5] = f2bf(f1.y); v[6] = f2bf(f1.z); v[7] = f2bf(f1.w);
            } else {
                #pragma unroll
                for (int j = 0; j < 8; ++j) v[j] = 0;
            }
            int off = row * 256 + (((c0 + i * 8) * 2) ^ sw);
            *(bf16x8*)((char*)As + off) = v;
        }
    }
    __syncthreads();

    int w = t >> 6, l = t & 63;
    int lr = l & 15, lk = l >> 4;
    int eloc = l >> 2, q = l & 3;   // epilogue: 4 lanes per edge
    int cb0 = w * 128;              // head pair base channel (w*2 heads * 64ch)

    bf16x8 pa0[2], pa1[2], pb0[2], pb1[2];
    f32x4 acc[4][4];

    // prefetch (hh=0, mi=0) before first MFMA loop
    PREF(eloc, cb0, 0);

    #pragma unroll
    for (int hh = 0; hh < 2; ++hh) {
        int cb = cb0 + hh * 64;
        int h = w * 2 + hh;

        #pragma unroll
        for (int mi = 0; mi < 4; ++mi)
            #pragma unroll
            for (int fj = 0; fj < 4; ++fj)
                #pragma unroll
                for (int qq = 0; qq < 4; ++qq) acc[mi][fj][qq] = 0.f;

        #pragma unroll
        for (int k0 = 0; k0 < 4; ++k0) {
            bf16x8 a4[4];
            #pragma unroll
            for (int mi = 0; mi < 4; ++mi) {
                int row = mi * 16 + lr;
                int off = row * 256 + ((k0 * 64 + lk * 16) ^ ((row & 7) << 4));
                a4[mi] = *(const bf16x8*)((const char*)As + off);
            }
            #pragma unroll
            for (int fj = 0; fj < 4; ++fj) {
                bf16x8 b = *(const bf16x8*)(WeT + (size_t)(cb + fj * 16 + lr) * 128 + k0 * 32 + lk * 8);
                #pragma unroll
                for (int mi = 0; mi < 4; ++mi)
                    acc[mi][fj] = __builtin_amdgcn_mfma_f32_16x16x32_bf16(a4[mi], b, acc[mi][fj], 0, 0, 0);
            }
        }

        #pragma unroll
        for (int mi = 0; mi < 4; ++mi) {
            // prefetch next round (double-buffered; indices static under unroll)
            if (mi < 3) { PREF(mi * 16 + 16 + eloc, cb, (mi + 1) & 1); }
            else if (hh == 0) { PREF(eloc, cb + 64, 0); }

            // transpose this mi-tile of xe through wave-private LDS
            #pragma unroll
            for (int fj = 0; fj < 4; ++fj)
                #pragma unroll
                for (int reg = 0; reg < 4; ++reg)
                    xeT[w][lk * 4 + reg][fj * 16 + lr] = acc[mi][fj][reg];

            const bf16x8 ca0 = pa0[mi & 1], ca1 = pa1[mi & 1];
            const bf16x8 cb0v = pb0[mi & 1], cb1v = pb1[mi & 1];

            float sum = 0.f;
            #pragma unroll
            for (int sg = 0; sg < 4; ++sg) {
                float4 xe4 = *(const float4*)&xeT[w][eloc][q * 16 + sg * 4];
                float4 av  = *(const float4*)&att_s[cb + q * 16 + sg * 4];
                float v0 = xe4.x + bfx(ca0, ca1, sg * 4 + 0) + bfx(cb0v, cb1v, sg * 4 + 0);
                float v1 = xe4.y + bfx(ca0, ca1, sg * 4 + 1) + bfx(cb0v, cb1v, sg * 4 + 1);
                float v2 = xe4.z + bfx(ca0, ca1, sg * 4 + 2) + bfx(cb0v, cb1v, sg * 4 + 2);
                float v3 = xe4.w + bfx(ca0, ca1, sg * 4 + 3) + bfx(cb0v, cb1v, sg * 4 + 3);
                v0 = (v0 > 0.f) ? v0 : v0 * NEG_SLOPE;
                v1 = (v1 > 0.f) ? v1 : v1 * NEG_SLOPE;
                v2 = (v2 > 0.f) ? v2 : v2 * NEG_SLOPE;
                v3 = (v3 > 0.f) ? v3 : v3 * NEG_SLOPE;
                sum = fmaf(av.x, v0, sum);
                sum = fmaf(av.y, v1, sum);
                sum = fmaf(av.z, v2, sum);
                sum = fmaf(av.w, v3, sum);
            }
            sum += __shfl_xor(sum, 1, 64);
            sum += __shfl_xor(sum, 2, 64);
            if (q == 0) {
                int p = row0 + mi * 16 + eloc;
                if (p < M_TOT) logits[(size_t)p * 8 + h] = sum;
            }
        }
    }
}

// ---------------- fused segment softmax + gather aggregation (p-ordered logits) ----------------
__global__ void k_agg(const int* __restrict__ rowptr, const int* __restrict__ src_s,
                      const float* __restrict__ logits,
                      const unsigned short* __restrict__ xlb, const float* __restrict__ bias,
                      float* __restrict__ out) {
    int node = (blockIdx.x * blockDim.x + threadIdx.x) >> 6;
    int lane = threadIdx.x & 63;
    if (node >= N_NODES) return;
    int beg = rowptr[node], end = rowptr[node + 1];
    int h = lane >> 3;

    float m = -3.4e38f;
    for (int p = beg; p < end; ++p) m = fmaxf(m, logits[(size_t)p * 8 + h]);
    float den = 0.f;
    for (int p = beg; p < end; ++p) den += __expf(logits[(size_t)p * 8 + h] - m);
    float rden = 1.f / den;

    float acc[8] = {};
    bf16x8 v_nxt = *(const bf16x8*)(xlb + (size_t)src_s[beg] * 512 + lane * 8);
    for (int p = beg; p < end; ++p) {
        bf16x8 v = v_nxt;
        float lg = logits[(size_t)p * 8 + h];
        if (p + 1 < end)
            v_nxt = *(const bf16x8*)(xlb + (size_t)src_s[p + 1] * 512 + lane * 8);
        float alpha = __expf(lg - m) * rden;
        #pragma unroll
        for (int j = 0; j < 8; ++j) acc[j] = fmaf(alpha, bf2f((unsigned short)v[j]), acc[j]);
    }
    float4* op = (float4*)(out + (size_t)node * 512 + lane * 8);
    const float4* bp = (const float4*)(bias + lane * 8);
    float4 bv0 = bp[0], bv1 = bp[1];
    float4 r0 = { acc[0] + bv0.x, acc[1] + bv0.y, acc[2] + bv0.z, acc[3] + bv0.w };
    float4 r1 = { acc[4] + bv1.x, acc[5] + bv1.y, acc[6] + bv1.z, acc[7] + bv1.w };
    op[0] = r0; op[1] = r1;
}

extern "C" void kernel_launch(void* const* d_in, const int* in_sizes, int n_in,
                              void* d_out, int out_size, void* d_ws, size_t ws_size,
                              hipStream_t stream) {
    const float* x    = (const float*)d_in[0];
    const int*   ei   = (const int*)d_in[1];
    const float* ea   = (const float*)d_in[2];
    const float* Wl   = (const float*)d_in[3];
    const float* Wr   = (const float*)d_in[4];
    const float* We   = (const float*)d_in[5];
    const float* att  = (const float*)d_in[6];
    const float* bias = (const float*)d_in[7];
    float* out = (float*)d_out;

    unsigned short* xlb = (unsigned short*)d_ws;             // N*512 bf16
    unsigned short* xrb = xlb + (size_t)N_NODES * HC;        // N*512 bf16
    unsigned short* WlT = xrb + (size_t)N_NODES * HC;        // 512*128 bf16
    unsigned short* WrT = WlT + HC * IN_CH;
    unsigned short* WeT = WrT + HC * IN_CH;
    float* loop_attr = (float*)(WeT + HC * IN_CH);           // N*128 f32
    float* logits    = loop_attr + (size_t)N_NODES * IN_CH;  // M_TOT*8 f32
    int* deg         = (int*)(logits + (size_t)M_TOT * 8);
    int* rowptr      = deg + N_NODES;
    int* cursor      = rowptr + N_NODES + 1;
    int* eidx        = cursor + N_NODES;
    int* src_s       = eidx + M_TOT;
    int* dst_s       = src_s + M_TOT;

    const int B = 256;
    k_zero<<<(N_NODES + B - 1) / B, B, 0, stream>>>(deg);
    k_deg<<<(E_EDGES + B - 1) / B, B, 0, stream>>>(ei, deg);
    k_scan<<<1, B, 0, stream>>>(deg, rowptr, cursor, eidx, src_s, dst_s);
    k_fill<<<(E_EDGES + B - 1) / B, B, 0, stream>>>(ei, cursor, eidx, src_s, dst_s);
    k_loop_attr<<<(N_NODES * 64 + B - 1) / B, B, 0, stream>>>(rowptr, eidx, ea, loop_attr);
    k_trans<<<(HC * IN_CH + B - 1) / B, B, 0, stream>>>(Wl, WlT);
    k_trans<<<(HC * IN_CH + B - 1) / B, B, 0, stream>>>(Wr, WrT);
    k_trans<<<(HC * IN_CH + B - 1) / B, B, 0, stream>>>(We, WeT);
    k_gemm2<<<dim3((N_NODES + 63) / 64, 4), B, 0, stream>>>(x, WlT, WrT, xlb, xrb, N_NODES);
    k_logits_mfma<<<(M_TOT + 63) / 64, B, 0, stream>>>(eidx, src_s, dst_s, ea, loop_attr,
                                                       WeT, xlb, xrb, att, logits);
    k_agg<<<((size_t)N_NODES * 64 + B - 1) / B, B, 0, stream>>>(rowptr, src_s, logits, xlb, bias, out);
}

// Round 6
// 257.234 us; speedup vs baseline: 12.6252x; 1.3515x over previous
//
#include <hip/hip_runtime.h>

#define N_NODES 20000
#define E_EDGES 160000
#define IN_CH 128
#define H_HEADS 8
#define C_CH 64
#define HC 512
#define M_TOT (E_EDGES + N_NODES)
#define NEG_SLOPE 0.2f
#define NCHUNK ((N_NODES + 255) / 256)

typedef __attribute__((ext_vector_type(8))) short bf16x8;
typedef __attribute__((ext_vector_type(4))) float f32x4;

__device__ __forceinline__ unsigned short f2bf(float f) {
    unsigned u = __float_as_uint(f);
    unsigned r = (u + 0x7FFFu + ((u >> 16) & 1u)) >> 16;   // RNE
    return (unsigned short)r;
}
__device__ __forceinline__ float bf2f(unsigned short s) {
    return __uint_as_float((unsigned)s << 16);
}
__device__ __forceinline__ float bfx(const bf16x8& v0, const bf16x8& v1, int idx) {
    return bf2f((unsigned short)((idx < 8) ? v0[idx] : v1[idx - 8]));
}

// ---------------- CSR build ----------------
__global__ void k_deg(const int* __restrict__ ei, int* __restrict__ deg) {
    int e = blockIdx.x * blockDim.x + threadIdx.x;
    if (e >= E_EDGES) return;
    atomicAdd(&deg[ei[E_EDGES + e]], 1);
}

__global__ void k_scan1(const int* __restrict__ deg, int* __restrict__ bsum) {
    __shared__ int red[256];
    int tid = threadIdx.x;
    int i = blockIdx.x * 256 + tid;
    red[tid] = (i < N_NODES) ? deg[i] + 1 : 0;
    __syncthreads();
    for (int off = 128; off > 0; off >>= 1) {
        if (tid < off) red[tid] += red[tid + off];
        __syncthreads();
    }
    if (tid == 0) bsum[blockIdx.x] = red[0];
}

__global__ void k_scan2(const int* __restrict__ bsum, int* __restrict__ boff) {
    if (threadIdx.x == 0) {
        int run = 0;
        for (int b = 0; b < NCHUNK; ++b) { boff[b] = run; run += bsum[b]; }
    }
}

__global__ void k_scan3(const int* __restrict__ deg, const int* __restrict__ boff,
                        int* __restrict__ rowptr, int* __restrict__ cursor,
                        int* __restrict__ eidx, int* __restrict__ src_s,
                        int* __restrict__ dst_s) {
    __shared__ int buf[256];
    int tid = threadIdx.x;
    int i = blockIdx.x * 256 + tid;
    int v = (i < N_NODES) ? deg[i] + 1 : 0;
    buf[tid] = v;
    __syncthreads();
    for (int off = 1; off < 256; off <<= 1) {
        int tv = (tid >= off) ? buf[tid - off] : 0;
        __syncthreads();
        buf[tid] += tv;
        __syncthreads();
    }
    if (i < N_NODES) {
        int excl = boff[blockIdx.x] + buf[tid] - v;
        rowptr[i] = excl;
        eidx[excl] = E_EDGES + i;   // self-loop edge in slot 0
        src_s[excl] = i;
        dst_s[excl] = i;
        cursor[i] = excl + 1;
        if (i == N_NODES - 1) rowptr[N_NODES] = excl + v;   // == M_TOT
    }
}

__global__ void k_fill(const int* __restrict__ ei, int* __restrict__ cursor,
                       int* __restrict__ eidx, int* __restrict__ src_s,
                       int* __restrict__ dst_s) {
    int e = blockIdx.x * blockDim.x + threadIdx.x;
    if (e >= E_EDGES) return;
    int d = ei[E_EDGES + e];
    int slot = atomicAdd(&cursor[d], 1);
    eidx[slot] = e;
    src_s[slot] = ei[e];
    dst_s[slot] = d;
}

// ---------------- loop_attr = mean of incoming edge_attr (slot0 = self loop, skip) ----------------
__global__ void k_loop_attr(const int* __restrict__ rowptr, const int* __restrict__ eidx,
                            const float* __restrict__ ea, float* __restrict__ loop_attr) {
    int wave = (blockIdx.x * blockDim.x + threadIdx.x) >> 6;
    int lane = threadIdx.x & 63;
    if (wave >= N_NODES) return;
    int beg = rowptr[wave] + 1, end = rowptr[wave + 1];
    int cnt = end - beg;
    float s0 = 0.f, s1 = 0.f;
    if (beg < end) {
        const float* p_nxt = ea + (size_t)eidx[beg] * 128 + lane;
        for (int p = beg; p < end; ++p) {
            const float* cur = p_nxt;
            if (p + 1 < end) p_nxt = ea + (size_t)eidx[p + 1] * 128 + lane;
            s0 += cur[0];
            s1 += cur[64];
        }
    }
    float inv = 1.f / fmaxf((float)cnt, 1.f);
    loop_attr[(size_t)wave * 128 + lane] = s0 * inv;
    loop_attr[(size_t)wave * 128 + 64 + lane] = s1 * inv;
}

// ---------------- weight transpose + bf16 (all three) ----------------
__global__ void k_trans3(const float* __restrict__ Wl, const float* __restrict__ Wr,
                         const float* __restrict__ We,
                         unsigned short* __restrict__ WlT, unsigned short* __restrict__ WrT,
                         unsigned short* __restrict__ WeT) {
    int idx = blockIdx.x * blockDim.x + threadIdx.x;
    if (idx >= HC * IN_CH) return;
    int m = blockIdx.y;
    const float* W = (m == 0) ? Wl : (m == 1) ? Wr : We;
    unsigned short* WT = (m == 0) ? WlT : (m == 1) ? WrT : WeT;
    int n = idx >> 7, k = idx & 127;
    WT[idx] = f2bf(W[(size_t)k * HC + n]);
}

// ---------------- merged dual MFMA GEMM: xlb = bf16(x@Wl), xrb = bf16(x@Wr) ----------------
__global__ void k_gemm2(const float* __restrict__ A,
                        const unsigned short* __restrict__ WlT,
                        const unsigned short* __restrict__ WrT,
                        unsigned short* __restrict__ xlb, unsigned short* __restrict__ xrb,
                        int M) {
    __shared__ short As[64 * 128];
    int row0 = blockIdx.x * 64;
    int sel = blockIdx.y >> 1;
    const unsigned short* BT = sel ? WrT : WlT;
    unsigned short* Cb = sel ? xrb : xlb;
    int t = threadIdx.x;
    {
        int row = t >> 2, c0 = (t & 3) * 32;
        int gr = row0 + row;
        int sw = (row & 7) << 4;
        const float* src = A + (size_t)gr * 128 + c0;
        #pragma unroll
        for (int i = 0; i < 4; ++i) {
            bf16x8 v;
            if (gr < M) {
                const float4* p = (const float4*)(src + i * 8);
                float4 f0 = p[0], f1 = p[1];
                v[0] = f2bf(f0.x); v[1] = f2bf(f0.y); v[2] = f2bf(f0.z); v[3] = f2bf(f0.w);
                v[4] = f2bf(f1.x); v[5] = f2bf(f1.y); v[6] = f2bf(f1.z); v[7] = f2bf(f1.w);
            } else {
                #pragma unroll
                for (int j = 0; j < 8; ++j) v[j] = 0;
            }
            int off = row * 256 + (((c0 + i * 8) * 2) ^ sw);
            *(bf16x8*)((char*)As + off) = v;
        }
    }
    __syncthreads();

    int w = t >> 6, l = t & 63;
    int lr = l & 15, lk = l >> 4;
    int col0 = (blockIdx.y & 1) * 256 + w * 64;

    f32x4 acc[4][4];
    #pragma unroll
    for (int mi = 0; mi < 4; ++mi)
        #pragma unroll
        for (int fj = 0; fj < 4; ++fj)
            #pragma unroll
            for (int q = 0; q < 4; ++q) acc[mi][fj][q] = 0.f;

    #pragma unroll
    for (int k0 = 0; k0 < 4; ++k0) {
        bf16x8 a4[4];
        #pragma unroll
        for (int mi = 0; mi < 4; ++mi) {
            int row = mi * 16 + lr;
            int off = row * 256 + ((k0 * 64 + lk * 16) ^ ((row & 7) << 4));
            a4[mi] = *(const bf16x8*)((const char*)As + off);
        }
        #pragma unroll
        for (int fj = 0; fj < 4; ++fj) {
            bf16x8 b = *(const bf16x8*)(BT + (size_t)(col0 + fj * 16 + lr) * 128 + k0 * 32 + lk * 8);
            #pragma unroll
            for (int mi = 0; mi < 4; ++mi)
                acc[mi][fj] = __builtin_amdgcn_mfma_f32_16x16x32_bf16(a4[mi], b, acc[mi][fj], 0, 0, 0);
        }
    }
    #pragma unroll
    for (int mi = 0; mi < 4; ++mi) {
        #pragma unroll
        for (int reg = 0; reg < 4; ++reg) {
            int r = row0 + mi * 16 + lk * 4 + reg;
            if (r < M) {
                unsigned short* cp = Cb + (size_t)r * 512 + col0 + lr;
                #pragma unroll
                for (int fj = 0; fj < 4; ++fj) cp[fj * 16] = f2bf(acc[mi][fj][reg]);
            }
        }
    }
}

// ---------------- fused: edge GEMM + scoring + interior softmax/aggregation ----------------
#define PREF(R, CB, SLOT) { \
    int s_ = s_src[R], d_ = s_dst[R]; \
    const bf16x8* xp_ = (const bf16x8*)(xlb + (size_t)s_ * 512 + (CB) + q * 16); \
    pa0[SLOT] = xp_[0]; pa1[SLOT] = xp_[1]; \
    const bf16x8* rp_ = (const bf16x8*)(xrb + (size_t)d_ * 512 + (CB) + q * 16); \
    pb0[SLOT] = rp_[0]; pb1[SLOT] = rp_[1]; }

__global__ void k_fused(const int* __restrict__ eidx, const int* __restrict__ src_s,
                        const int* __restrict__ dst_s, const int* __restrict__ rowptr,
                        const float* __restrict__ ea, const float* __restrict__ loop_attr,
                        const unsigned short* __restrict__ WeT,
                        const unsigned short* __restrict__ xlb,
                        const unsigned short* __restrict__ xrb,
                        const float* __restrict__ att, const float* __restrict__ bias,
                        float* __restrict__ logits, float* __restrict__ out) {
    __shared__ short As[64 * 128];
    __shared__ float xeT[4][16][68];
    __shared__ float att_s[512];
    __shared__ float lg[64][8];
    __shared__ int s_src[64], s_dst[64];
    __shared__ int own_node[64], own_beg[64], own_len[64];
    __shared__ int n_own;
    int row0 = blockIdx.x * 64;
    int t = threadIdx.x;

    if (t == 0) n_own = 0;
    __syncthreads();

    if (t < 64) {
        int p = row0 + t;
        int s = 0, d = 0;
        if (p < M_TOT) {
            s = src_s[p]; d = dst_s[p];
            int pb = rowptr[d], pe = rowptr[d + 1];
            if (pb == p && pe <= row0 + 64) {          // interior segment, first row
                int idx = atomicAdd(&n_own, 1);
                own_node[idx] = d; own_beg[idx] = t; own_len[idx] = pe - pb;
            }
        }
        s_src[t] = s; s_dst[t] = d;
    }
    att_s[t] = att[t];
    att_s[t + 256] = att[t + 256];
    {
        int row = t >> 2, c0 = (t & 3) * 32;
        int p = row0 + row;
        int sw = (row & 7) << 4;
        const float* src = nullptr;
        if (p < M_TOT) {
            int e = eidx[p];
            src = (e < E_EDGES) ? ea + (size_t)e * 128 + c0
                                : loop_attr + (size_t)(e - E_EDGES) * 128 + c0;
        }
        #pragma unroll
        for (int i = 0; i < 4; ++i) {
            bf16x8 v;
            if (src) {
                const float4* p4 = (const float4*)(src + i * 8);
                float4 f0 = p4[0], f1 = p4[1];
                v[0] = f2bf(f0.x); v[1] = f2bf(f0.y); v[2] = f2bf(f0.z); v[3] = f2bf(f0.w);
                v[4] = f2bf(f1.x); v[5] = f2bf(f1.y); v[6] = f2bf(f1.z); v[7] = f2bf(f1.w);
            } else {
                #pragma unroll
                for (int j = 0; j < 8; ++j) v[j] = 0;
            }
            int off = row * 256 + (((c0 + i * 8) * 2) ^ sw);
            *(bf16x8*)((char*)As + off) = v;
        }
    }
    __syncthreads();

    int w = t >> 6, l = t & 63;
    int lr = l & 15, lk = l >> 4;
    int eloc = l >> 2, q = l & 3;   // epilogue: 4 lanes per edge
    int cb0 = w * 128;              // head pair base channel

    bf16x8 pa0[2], pa1[2], pb0[2], pb1[2];
    f32x4 acc[4][4];

    PREF(eloc, cb0, 0);

    #pragma unroll
    for (int hh = 0; hh < 2; ++hh) {
        int cb = cb0 + hh * 64;
        int h = w * 2 + hh;

        #pragma unroll
        for (int mi = 0; mi < 4; ++mi)
            #pragma unroll
            for (int fj = 0; fj < 4; ++fj)
                #pragma unroll
                for (int qq = 0; qq < 4; ++qq) acc[mi][fj][qq] = 0.f;

        #pragma unroll
        for (int k0 = 0; k0 < 4; ++k0) {
            bf16x8 a4[4];
            #pragma unroll
            for (int mi = 0; mi < 4; ++mi) {
                int row = mi * 16 + lr;
                int off = row * 256 + ((k0 * 64 + lk * 16) ^ ((row & 7) << 4));
                a4[mi] = *(const bf16x8*)((const char*)As + off);
            }
            #pragma unroll
            for (int fj = 0; fj < 4; ++fj) {
                bf16x8 b = *(const bf16x8*)(WeT + (size_t)(cb + fj * 16 + lr) * 128 + k0 * 32 + lk * 8);
                #pragma unroll
                for (int mi = 0; mi < 4; ++mi)
                    acc[mi][fj] = __builtin_amdgcn_mfma_f32_16x16x32_bf16(a4[mi], b, acc[mi][fj], 0, 0, 0);
            }
        }

        #pragma unroll
        for (int mi = 0; mi < 4; ++mi) {
            if (mi < 3) { PREF(mi * 16 + 16 + eloc, cb, (mi + 1) & 1); }
            else if (hh == 0) { PREF(eloc, cb + 64, 0); }

            #pragma unroll
            for (int fj = 0; fj < 4; ++fj)
                #pragma unroll
                for (int reg = 0; reg < 4; ++reg)
                    xeT[w][lk * 4 + reg][fj * 16 + lr] = acc[mi][fj][reg];

            const bf16x8 ca0 = pa0[mi & 1], ca1 = pa1[mi & 1];
            const bf16x8 cb0v = pb0[mi & 1], cb1v = pb1[mi & 1];

            float sum = 0.f;
            #pragma unroll
            for (int sg = 0; sg < 4; ++sg) {
                float4 xe4 = *(const float4*)&xeT[w][eloc][q * 16 + sg * 4];
                float4 av  = *(const float4*)&att_s[cb + q * 16 + sg * 4];
                float v0 = xe4.x + bfx(ca0, ca1, sg * 4 + 0) + bfx(cb0v, cb1v, sg * 4 + 0);
                float v1 = xe4.y + bfx(ca0, ca1, sg * 4 + 1) + bfx(cb0v, cb1v, sg * 4 + 1);
                float v2 = xe4.z + bfx(ca0, ca1, sg * 4 + 2) + bfx(cb0v, cb1v, sg * 4 + 2);
                float v3 = xe4.w + bfx(ca0, ca1, sg * 4 + 3) + bfx(cb0v, cb1v, sg * 4 + 3);
                v0 = (v0 > 0.f) ? v0 : v0 * NEG_SLOPE;
                v1 = (v1 > 0.f) ? v1 : v1 * NEG_SLOPE;
                v2 = (v2 > 0.f) ? v2 : v2 * NEG_SLOPE;
                v3 = (v3 > 0.f) ? v3 : v3 * NEG_SLOPE;
                sum = fmaf(av.x, v0, sum);
                sum = fmaf(av.y, v1, sum);
                sum = fmaf(av.z, v2, sum);
                sum = fmaf(av.w, v3, sum);
            }
            sum += __shfl_xor(sum, 1, 64);
            sum += __shfl_xor(sum, 2, 64);
            if (q == 0) {
                int rloc = mi * 16 + eloc;
                lg[rloc][h] = sum;
                int p = row0 + rloc;
                if (p < M_TOT) logits[(size_t)p * 8 + h] = sum;
            }
        }
    }
    __syncthreads();

    // interior softmax + aggregation (owned segments, logits in LDS, xl hot in L1/L2)
    {
        int lane = t & 63;
        int h = lane >> 3;
        for (int o = w; o < n_own; o += 4) {
            int d = own_node[o], rb = own_beg[o], len = own_len[o];
            float m = -3.4e38f;
            for (int j = 0; j < len; ++j) m = fmaxf(m, lg[rb + j][h]);
            float den = 0.f;
            for (int j = 0; j < len; ++j) den += __expf(lg[rb + j][h] - m);
            float rden = 1.f / den;
            float ac[8] = {};
            bf16x8 v_nxt = *(const bf16x8*)(xlb + (size_t)s_src[rb] * 512 + lane * 8);
            for (int j = 0; j < len; ++j) {
                bf16x8 v = v_nxt;
                if (j + 1 < len)
                    v_nxt = *(const bf16x8*)(xlb + (size_t)s_src[rb + j + 1] * 512 + lane * 8);
                float alpha = __expf(lg[rb + j][h] - m) * rden;
                #pragma unroll
                for (int jj = 0; jj < 8; ++jj) ac[jj] = fmaf(alpha, bf2f((unsigned short)v[jj]), ac[jj]);
            }
            float4* op = (float4*)(out + (size_t)d * 512 + lane * 8);
            const float4* bp = (const float4*)(bias + lane * 8);
            float4 bv0 = bp[0], bv1 = bp[1];
            float4 r0 = { ac[0] + bv0.x, ac[1] + bv0.y, ac[2] + bv0.z, ac[3] + bv0.w };
            float4 r1 = { ac[4] + bv1.x, ac[5] + bv1.y, ac[6] + bv1.z, ac[7] + bv1.w };
            op[0] = r0; op[1] = r1;
        }
    }
}

// ---------------- cleanup: boundary segments only ----------------
__global__ void k_cleanup(const int* __restrict__ rowptr, const int* __restrict__ src_s,
                          const float* __restrict__ logits,
                          const unsigned short* __restrict__ xlb, const float* __restrict__ bias,
                          float* __restrict__ out) {
    int node = (blockIdx.x * blockDim.x + threadIdx.x) >> 6;
    int lane = threadIdx.x & 63;
    if (node >= N_NODES) return;
    int beg = rowptr[node], end = rowptr[node + 1];
    if ((beg >> 6) == ((end - 1) >> 6)) return;   // interior: handled in k_fused
    int h = lane >> 3;

    float m = -3.4e38f;
    for (int p = beg; p < end; ++p) m = fmaxf(m, logits[(size_t)p * 8 + h]);
    float den = 0.f;
    for (int p = beg; p < end; ++p) den += __expf(logits[(size_t)p * 8 + h] - m);
    float rden = 1.f / den;

    float acc[8] = {};
    bf16x8 v_nxt = *(const bf16x8*)(xlb + (size_t)src_s[beg] * 512 + lane * 8);
    for (int p = beg; p < end; ++p) {
        bf16x8 v = v_nxt;
        float lgv = logits[(size_t)p * 8 + h];
        if (p + 1 < end)
            v_nxt = *(const bf16x8*)(xlb + (size_t)src_s[p + 1] * 512 + lane * 8);
        float alpha = __expf(lgv - m) * rden;
        #pragma unroll
        for (int j = 0; j < 8; ++j) acc[j] = fmaf(alpha, bf2f((unsigned short)v[j]), acc[j]);
    }
    float4* op = (float4*)(out + (size_t)node * 512 + lane * 8);
    const float4* bp = (const float4*)(bias + lane * 8);
    float4 bv0 = bp[0], bv1 = bp[1];
    float4 r0 = { acc[0] + bv0.x, acc[1] + bv0.y, acc[2] + bv0.z, acc[3] + bv0.w };
    float4 r1 = { acc[4] + bv1.x, acc[5] + bv1.y, acc[6] + bv1.z, acc[7] + bv1.w };
    op[0] = r0; op[1] = r1;
}

extern "C" void kernel_launch(void* const* d_in, const int* in_sizes, int n_in,
                              void* d_out, int out_size, void* d_ws, size_t ws_size,
                              hipStream_t stream) {
    const float* x    = (const float*)d_in[0];
    const int*   ei   = (const int*)d_in[1];
    const float* ea   = (const float*)d_in[2];
    const float* Wl   = (const float*)d_in[3];
    const float* Wr   = (const float*)d_in[4];
    const float* We   = (const float*)d_in[5];
    const float* att  = (const float*)d_in[6];
    const float* bias = (const float*)d_in[7];
    float* out = (float*)d_out;

    unsigned short* xlb = (unsigned short*)d_ws;             // N*512 bf16
    unsigned short* xrb = xlb + (size_t)N_NODES * HC;        // N*512 bf16
    unsigned short* WlT = xrb + (size_t)N_NODES * HC;        // 512*128 bf16
    unsigned short* WrT = WlT + HC * IN_CH;
    unsigned short* WeT = WrT + HC * IN_CH;
    float* loop_attr = (float*)(WeT + HC * IN_CH);           // N*128 f32
    float* logits    = loop_attr + (size_t)N_NODES * IN_CH;  // M_TOT*8 f32
    int* deg         = (int*)(logits + (size_t)M_TOT * 8);
    int* rowptr      = deg + N_NODES;
    int* cursor      = rowptr + N_NODES + 1;
    int* eidx        = cursor + N_NODES;
    int* src_s       = eidx + M_TOT;
    int* dst_s       = src_s + M_TOT;
    int* bsum        = dst_s + M_TOT;
    int* boff        = bsum + NCHUNK;

    const int B = 256;
    hipMemsetAsync(deg, 0, N_NODES * sizeof(int), stream);
    k_deg<<<(E_EDGES + B - 1) / B, B, 0, stream>>>(ei, deg);
    k_scan1<<<NCHUNK, B, 0, stream>>>(deg, bsum);
    k_scan2<<<1, 64, 0, stream>>>(bsum, boff);
    k_scan3<<<NCHUNK, B, 0, stream>>>(deg, boff, rowptr, cursor, eidx, src_s, dst_s);
    k_fill<<<(E_EDGES + B - 1) / B, B, 0, stream>>>(ei, cursor, eidx, src_s, dst_s);
    k_loop_attr<<<(N_NODES * 64 + B - 1) / B, B, 0, stream>>>(rowptr, eidx, ea, loop_attr);
    k_trans3<<<dim3((HC * IN_CH + B - 1) / B, 3), B, 0, stream>>>(Wl, Wr, We, WlT, WrT, WeT);
    k_gemm2<<<dim3((N_NODES + 63) / 64, 4), B, 0, stream>>>(x, WlT, WrT, xlb, xrb, N_NODES);
    k_fused<<<(M_TOT + 63) / 64, B, 0, stream>>>(eidx, src_s, dst_s, rowptr, ea, loop_attr,
                                                 WeT, xlb, xrb, att, bias, logits, out);
    k_cleanup<<<((size_t)N_NODES * 64 + B - 1) / B, B, 0, stream>>>(rowptr, src_s, logits,
                                                                    xlb, bias, out);
}